// Round 1
// baseline (472.775 us; speedup 1.0000x reference)
//
#include <hip/hip_runtime.h>
#include <hip/hip_bf16.h>
#include <math.h>

#define BB    256   // batch
#define LL    256   // seq len
#define NV    14    // vocab
#define EMBD  512
#define H2    128   // L//2
#define OC    256   // branch conv out channels
#define NP    196   // 14*14 ordered token pairs
#define JD    128   // branch linear out
#define KBIG  32768 // OC*H2
#define MO    64    // manip conv out channels
#define MJ    256   // manip linear out

// ---------- pair tables: P[br][q][c] = max(emb[t1][c], emb[t2][c]) ----------
__global__ void k_pairs(const float* __restrict__ emb_e, const float* __restrict__ emb_f,
                        float* __restrict__ P) {
    int q  = blockIdx.x % NP;
    int br = blockIdx.x / NP;
    const float* emb = br ? emb_f : emb_e;
    int t1 = q / NV, t2 = q % NV;
    float* outp = P + ((size_t)br * NP + q) * EMBD;
    for (int c = threadIdx.x; c < EMBD; c += blockDim.x)
        outp[c] = fmaxf(emb[t1 * EMBD + c], emb[t2 * EMBD + c]);
}

// ---------- transpose conv weights (kw=1 column only): cwT[br][kh][i][o] ----------
__global__ void k_cwt(const float* __restrict__ cw_e, const float* __restrict__ cw_f,
                      float* __restrict__ cwT) {
    int idx = blockIdx.x * blockDim.x + threadIdx.x;  // 2*3*512*256 total
    int o = idx & 255;
    int i = (idx >> 8) & 511;
    int rest = idx >> 17;       // 0..5
    int kh = rest % 3;
    int br = rest / 3;
    const float* cw = br ? cw_f : cw_e;
    cwT[idx] = cw[((size_t)(o * EMBD + i) * 3 + kh) * 3 + 1];
}

// ---------- manip conv weight folds: Wc[cls][i][o], cls0:h=0 (kh 1,2) cls1:int (all) cls2:h=127 (kh 0,1) ----------
__global__ void k_manipw(const float* __restrict__ mcw, float* __restrict__ Wc) {
    int idx = blockIdx.x * blockDim.x + threadIdx.x;  // 3*128*64
    int o = idx & 63;
    int i = (idx >> 6) & 127;
    int cls = idx >> 13;  // 0..2
    const float* base = mcw + ((size_t)(o * 128 + i) * 3) * 3 + 1;  // kh stride = 3
    float v = 0.f;
    if (cls != 2) { v += base[3]; v += base[6]; }   // kh=1,2
    else          { v += base[0]; v += base[3]; }   // kh=0,1
    if (cls == 1)   v += base[0];                    // interior adds kh=0 too
    Wc[idx] = v;
}

// ---------- interior column-sum of manip_lin_w: Lint[o][j] = sum_{h=1..126} mlw[(o*128+h)*256+j] ----------
__global__ void k_lint(const float* __restrict__ mlw, float* __restrict__ Lint) {
    int idx = blockIdx.x * blockDim.x + threadIdx.x;  // 64*256
    int j = idx & 255;
    int o = idx >> 8;
    float s = 0.f;
    for (int h = 1; h <= 126; h++)
        s += mlw[((size_t)(o * H2 + h)) * MJ + j];
    Lint[idx] = s;
}

// ---------- pair contributions: C[br][q][kh][o] = sum_i cwT[br][kh][i][o] * P[br][q][i] ----------
__global__ void k_contrib(const float* __restrict__ P, const float* __restrict__ cwT,
                          float* __restrict__ C) {
    int bid = blockIdx.x;         // 2*3*28
    int qg = bid % 28;
    int kh = (bid / 28) % 3;
    int br = bid / 84;
    int o = threadIdx.x;
    const float* w  = cwT + ((size_t)(br * 3 + kh) * EMBD) * OC + o;
    const float* Pb = P + ((size_t)br * NP + qg * 7) * EMBD;
    float acc[7];
    #pragma unroll
    for (int qq = 0; qq < 7; qq++) acc[qq] = 0.f;
    for (int i = 0; i < EMBD; i++) {
        float wv = w[(size_t)i * OC];
        #pragma unroll
        for (int qq = 0; qq < 7; qq++) acc[qq] += wv * Pb[(size_t)qq * EMBD + i];
    }
    #pragma unroll
    for (int qq = 0; qq < 7; qq++)
        C[(((size_t)br * NP + qg * 7 + qq) * 3 + kh) * OC + o] = acc[qq];
}

// ---------- conv-output assembly: y[b][h][o] = cb[o] + sum_kh C[q(b,h-1+kh)][kh][o] ----------
__global__ void k_assembly(const int* __restrict__ tok, const float* __restrict__ C,
                           const float* __restrict__ cb, float* __restrict__ y) {
    int b = blockIdx.x >> 7;
    int h = blockIdx.x & 127;
    int o = threadIdx.x;
    const int* tb = tok + (size_t)b * LL;
    int q1 = tb[2 * h] * NV + tb[2 * h + 1];
    float v = cb[o] + C[((size_t)q1 * 3 + 1) * OC + o];
    if (h > 0) {
        int q0 = tb[2 * h - 2] * NV + tb[2 * h - 1];
        v += C[((size_t)q0 * 3 + 0) * OC + o];
    }
    if (h < H2 - 1) {
        int q2 = tb[2 * h + 2] * NV + tb[2 * h + 3];
        v += C[((size_t)q2 * 3 + 2) * OC + o];
    }
    y[(size_t)b * KBIG + h * OC + o] = v;
}

// ---------- big linear, split-K: partial[kc][b][j] = sum_{k in chunk} y[b][k] * lw[k][j] ----------
__global__ void k_biglin(const float* __restrict__ y, const float* __restrict__ lw,
                         float* __restrict__ partial) {
    int kc = blockIdx.x;          // 0..31 (o-range of 8)
    int bg = blockIdx.y;          // 0..15 (16 b per block)
    int j    = threadIdx.x & 127;
    int half = threadIdx.x >> 7;
    int b0 = bg * 16 + half * 8;
    float acc[8];
    #pragma unroll
    for (int r = 0; r < 8; r++) acc[r] = 0.f;
    for (int oo = 0; oo < 8; oo++) {
        int o = kc * 8 + oo;
        const float* lwo = lw + (size_t)o * H2 * JD + j;
        const float* yo  = y + (size_t)b0 * KBIG + o;
        for (int h = 0; h < H2; h++) {
            float wv = lwo[(size_t)h * JD];
            const float* yb = yo + (size_t)h * OC;
            #pragma unroll
            for (int r = 0; r < 8; r++) acc[r] += yb[(size_t)r * KBIG] * wv;
        }
    }
    #pragma unroll
    for (int r = 0; r < 8; r++)
        partial[((size_t)kc * BB + (b0 + r)) * JD + j] = acc[r];
}

// ---------- reduce partials + bias (+ optional row softmax) ----------
template <int DO_SM>
__global__ void k_reduce(const float* __restrict__ partial, const float* __restrict__ bias,
                         float* __restrict__ outp) {
    int b = blockIdx.x;
    int j = threadIdx.x;  // 128
    float s = bias[j];
    for (int kc = 0; kc < 32; kc++)
        s += partial[((size_t)kc * BB + b) * JD + j];
    if (DO_SM) {
        __shared__ float red[JD];
        red[j] = s;
        __syncthreads();
        for (int st = 64; st > 0; st >>= 1) {
            if (j < st) red[j] = fmaxf(red[j], red[j + st]);
            __syncthreads();
        }
        float mx = red[0];
        __syncthreads();
        float e = expf(s - mx);
        red[j] = e;
        __syncthreads();
        for (int st = 64; st > 0; st >>= 1) {
            if (j < st) red[j] += red[j + st];
            __syncthreads();
        }
        outp[(size_t)b * JD + j] = e / red[0];
    } else {
        outp[(size_t)b * JD + j] = s;
    }
}

// ---------- manip conv values: m3[cls][b][o] = relu(mcb[o] + sum_i eo[b][i]*Wc[cls][i][o]) ----------
__global__ void k_mvals(const float* __restrict__ eo, const float* __restrict__ Wc,
                        const float* __restrict__ mcb, float* __restrict__ m3) {
    int idx = blockIdx.x * blockDim.x + threadIdx.x;  // 3*256*64
    int o = idx & 63;
    int b = (idx >> 6) & 255;
    int cls = idx >> 14;
    float acc = mcb[o];
    const float* w = Wc + (size_t)(cls * 128) * 64 + o;
    const float* e = eo + (size_t)b * JD;
    for (int i = 0; i < 128; i++) acc += e[i] * w[(size_t)i * 64];
    m3[idx] = fmaxf(acc, 0.f);
}

// ---------- manip linear + token quantization ----------
__global__ void k_m2tok(const float* __restrict__ m3, const float* __restrict__ mlw,
                        const float* __restrict__ Lint, const float* __restrict__ mlb,
                        int* __restrict__ tokens) {
    int j = threadIdx.x;   // 256
    int b = blockIdx.x;    // 256
    float acc = mlb[j];
    const float* m0p = m3 + (size_t)(0 * BB + b) * MO;
    const float* mip = m3 + (size_t)(1 * BB + b) * MO;
    const float* m1p = m3 + (size_t)(2 * BB + b) * MO;
    for (int o = 0; o < MO; o++) {
        acc += m0p[o] * mlw[((size_t)(o * H2 + 0)) * MJ + j];
        acc += mip[o] * Lint[(size_t)o * MJ + j];
        acc += m1p[o] * mlw[((size_t)(o * H2 + 127)) * MJ + j];
    }
    int t = ((int)floorf(fabsf(acc) * 100.f)) % NV;
    tokens[(size_t)b * LL + j] = t;
}

// ---------- final: f1 @ lin2 + b2, row softmax over 14 ----------
__global__ void k_final(const float* __restrict__ f1, const float* __restrict__ fl2,
                        const float* __restrict__ fb2, float* __restrict__ outp) {
    int b = blockIdx.x;
    int v = threadIdx.x;  // 64
    __shared__ float sl[NV];
    if (v < NV) {
        float acc = fb2[v];
        const float* fr = f1 + (size_t)b * JD;
        for (int jj = 0; jj < JD; jj++) acc += fr[jj] * fl2[(size_t)jj * NV + v];
        sl[v] = acc;
    }
    __syncthreads();
    if (v < NV) {
        float mx = -1e30f;
        for (int u = 0; u < NV; u++) mx = fmaxf(mx, sl[u]);
        float s = 0.f;
        for (int u = 0; u < NV; u++) s += expf(sl[u] - mx);
        outp[(size_t)b * NV + v] = expf(sl[v] - mx) / s;
    }
}

extern "C" void kernel_launch(void* const* d_in, const int* in_sizes, int n_in,
                              void* d_out, int out_size, void* d_ws, size_t ws_size,
                              hipStream_t stream) {
    const int*   x    = (const int*)d_in[0];
    const float* eemb = (const float*)d_in[1];
    const float* ecw  = (const float*)d_in[2];
    const float* ecb  = (const float*)d_in[3];
    const float* elw  = (const float*)d_in[4];
    const float* elb  = (const float*)d_in[5];
    // d_in[6] rand_proj: provably unused (fog_of_war returns identity permutation)
    const float* mcw  = (const float*)d_in[7];
    const float* mcb  = (const float*)d_in[8];
    const float* mlw  = (const float*)d_in[9];
    const float* mlb  = (const float*)d_in[10];
    const float* femb = (const float*)d_in[11];
    const float* fcw  = (const float*)d_in[12];
    const float* fcb  = (const float*)d_in[13];
    const float* flw1 = (const float*)d_in[14];
    const float* flb1 = (const float*)d_in[15];
    const float* fl2  = (const float*)d_in[16];
    const float* fb2  = (const float*)d_in[17];
    float* outp = (float*)d_out;

    char* w = (char*)d_ws;
    size_t off = 0;
    auto alloc = [&](size_t bytes) {
        void* p = w + off;
        off = (off + bytes + 255) & ~(size_t)255;
        return p;
    };
    float* P      = (float*)alloc(2ull * NP * EMBD * 4);        // 0.8 MB
    float* cwT    = (float*)alloc(2ull * 3 * EMBD * OC * 4);    // 3.1 MB
    float* C      = (float*)alloc(2ull * NP * 3 * OC * 4);      // 1.2 MB
    float* Wc     = (float*)alloc(3ull * 128 * 64 * 4);
    float* Lint   = (float*)alloc(64ull * MJ * 4);
    float* eo     = (float*)alloc((size_t)BB * JD * 4);
    float* m3     = (float*)alloc(3ull * BB * MO * 4);
    int*   tokens = (int*)alloc((size_t)BB * LL * 4);
    float* f1     = (float*)alloc((size_t)BB * JD * 4);
    float* y      = (float*)alloc((size_t)BB * KBIG * 4);       // 33.5 MB
    float* partial= (float*)alloc(32ull * BB * JD * 4);         // 4 MB

    const float* C_e = C;
    const float* C_f = C + (size_t)NP * 3 * OC;

    // ---- b-independent precomputation ----
    k_pairs<<<2 * NP, 256, 0, stream>>>(eemb, femb, P);
    k_cwt<<<(2 * 3 * EMBD * OC) / 256, 256, 0, stream>>>(ecw, fcw, cwT);
    k_manipw<<<(3 * 128 * 64) / 256, 256, 0, stream>>>(mcw, Wc);
    k_lint<<<(64 * MJ) / 256, 256, 0, stream>>>(mlw, Lint);
    k_contrib<<<2 * 3 * 28, 256, 0, stream>>>(P, cwT, C);

    // ---- enemy branch ----
    k_assembly<<<BB * H2, 256, 0, stream>>>(x, C_e, ecb, y);
    k_biglin<<<dim3(32, 16), 256, 0, stream>>>(y, elw, partial);
    k_reduce<1><<<BB, JD, 0, stream>>>(partial, elb, eo);   // softmax -> enemy_out

    // ---- manipulator + token quantization ----
    k_mvals<<<(3 * BB * MO) / 256, 256, 0, stream>>>(eo, Wc, mcb, m3);
    k_m2tok<<<BB, MJ, 0, stream>>>(m3, mlw, Lint, mlb, tokens);

    // ---- friend branch ----
    k_assembly<<<BB * H2, 256, 0, stream>>>(tokens, C_f, fcb, y);
    k_biglin<<<dim3(32, 16), 256, 0, stream>>>(y, flw1, partial);
    k_reduce<0><<<BB, JD, 0, stream>>>(partial, flb1, f1);

    // ---- head ----
    k_final<<<BB, 64, 0, stream>>>(f1, fl2, fb2, outp);
}

// Round 3
// 187.943 us; speedup vs baseline: 2.5155x; 2.5155x over previous
//
#include <hip/hip_runtime.h>
#include <hip/hip_bf16.h>
#include <math.h>

#define BB    256   // batch
#define LL    256   // seq len
#define NV    14    // vocab
#define EMBD  512
#define H2    128   // L//2
#define OC    256   // branch conv out channels
#define NP    196   // 14*14 ordered token pairs
#define JD    128   // branch linear out
#define MO    64    // manip conv out channels
#define MJ    256   // manip linear out
#define KK    32    // GEMM k-tile (o-chunk) per LDS stage

// ---------- pair tables: P[br][q][c] = max(emb[t1][c], emb[t2][c]) ----------
__global__ void k_pairs(const float* __restrict__ emb_e, const float* __restrict__ emb_f,
                        float* __restrict__ P) {
    int q  = blockIdx.x % NP;
    int br = blockIdx.x / NP;
    const float* emb = br ? emb_f : emb_e;
    int t1 = q / NV, t2 = q % NV;
    float* outp = P + ((size_t)br * NP + q) * EMBD;
    for (int c = threadIdx.x; c < EMBD; c += blockDim.x)
        outp[c] = fmaxf(emb[t1 * EMBD + c], emb[t2 * EMBD + c]);
}

// ---------- transpose conv weights (kw=1 column only): cwT[br][kh][i][o] ----------
__global__ void k_cwt(const float* __restrict__ cw_e, const float* __restrict__ cw_f,
                      float* __restrict__ cwT) {
    int idx = blockIdx.x * blockDim.x + threadIdx.x;  // 2*3*512*256 total
    int o = idx & 255;
    int i = (idx >> 8) & 511;
    int rest = idx >> 17;       // 0..5
    int kh = rest % 3;
    int br = rest / 3;
    const float* cw = br ? cw_f : cw_e;
    cwT[idx] = cw[((size_t)(o * EMBD + i) * 3 + kh) * 3 + 1];
}

// ---------- manip conv weight folds ----------
__global__ void k_manipw(const float* __restrict__ mcw, float* __restrict__ Wc) {
    int idx = blockIdx.x * blockDim.x + threadIdx.x;  // 3*128*64
    int o = idx & 63;
    int i = (idx >> 6) & 127;
    int cls = idx >> 13;  // 0..2
    const float* base = mcw + ((size_t)(o * 128 + i) * 3) * 3 + 1;  // kh stride = 3
    float v = 0.f;
    if (cls != 2) { v += base[3]; v += base[6]; }   // kh=1,2
    else          { v += base[0]; v += base[3]; }   // kh=0,1
    if (cls == 1)   v += base[0];                    // interior adds kh=0 too
    Wc[idx] = v;
}

// ---------- interior column-sum of manip_lin_w ----------
__global__ void k_lint(const float* __restrict__ mlw, float* __restrict__ Lint) {
    int idx = blockIdx.x * blockDim.x + threadIdx.x;  // 64*256
    int j = idx & 255;
    int o = idx >> 8;
    float s = 0.f;
    for (int h = 1; h <= 126; h++)
        s += mlw[((size_t)(o * H2 + h)) * MJ + j];
    Lint[idx] = s;
}

// ---------- pair contributions: C[br][q][kh][o] = sum_i cwT[br][kh][i][o] * P[br][q][i] ----------
__global__ void k_contrib(const float* __restrict__ P, const float* __restrict__ cwT,
                          float* __restrict__ C) {
    int bid = blockIdx.x;         // 2*3*28
    int qg = bid % 28;
    int kh = (bid / 28) % 3;
    int br = bid / 84;
    int o = threadIdx.x;
    const float* w  = cwT + ((size_t)(br * 3 + kh) * EMBD) * OC + o;
    const float* Pb = P + ((size_t)br * NP + qg * 7) * EMBD;
    float acc[7];
    #pragma unroll
    for (int qq = 0; qq < 7; qq++) acc[qq] = 0.f;
    for (int i = 0; i < EMBD; i++) {
        float wv = w[(size_t)i * OC];
        #pragma unroll
        for (int qq = 0; qq < 7; qq++) acc[qq] += wv * Pb[(size_t)qq * EMBD + i];
    }
    #pragma unroll
    for (int qq = 0; qq < 7; qq++)
        C[(((size_t)br * NP + qg * 7 + qq) * 3 + kh) * OC + o] = acc[qq];
}

// ---------- fused assembly + big linear (split-K over h) ----------
// out[b][j] = sum_{h,o} y[b,h,o] * lw[(o*H2+h)*JD + j]
// y[b,h,o] = cb[o] + C[q1][1][o] + C[q0][0][o] + C[q2][2][o]   (q's from tokens)
// block = (h, mt): M-tile 128 b's, N = 128 j's, K-chunk = 256 o's (one h).
// partial[h][b][j] accumulated; reduced by k_reduce.
__global__ __launch_bounds__(256) void k_branch_gemm(
        const int* __restrict__ tok, const float* __restrict__ C,
        const float* __restrict__ Cz, const float* __restrict__ cb,
        const float* __restrict__ lw, float* __restrict__ partial) {
    __shared__ __align__(16) float Yt[2][KK][132];   // [k][m], padded
    __shared__ __align__(16) float Wt[2][KK][128];   // [k][n]

    const int h  = blockIdx.x;            // 0..127
    const int b0 = blockIdx.y * 128;      // m-tile base
    const int t  = threadIdx.x;

    // --- per-thread gather rows (m = t>>1; two threads per m, one o-half each)
    const int m    = t >> 1;
    const int half = t & 1;
    const int* tb = tok + (size_t)(b0 + m) * LL;
    int q1 = tb[2 * h] * NV + tb[2 * h + 1];
    const float* r1 = C + ((size_t)q1 * 3 + 1) * OC;
    const float* r0 = Cz;
    const float* r2 = Cz;
    if (h > 0)      { int q0 = tb[2 * h - 2] * NV + tb[2 * h - 1]; r0 = C + ((size_t)q0 * 3 + 0) * OC; }
    if (h < H2 - 1) { int q2 = tb[2 * h + 2] * NV + tb[2 * h + 3]; r2 = C + ((size_t)q2 * 3 + 2) * OC; }

    // --- W staging mapping: thread loads 16 contiguous floats of one row
    const int wrow = t >> 3;              // 0..31
    const int wcol = (t & 7) * 16;        // 0,16,...,112
    const float* wbase = lw + ((size_t)wrow * H2 + h) * JD + wcol;

    // --- micro-tile mapping
    const int tm = t >> 4, tn = t & 15;
    const int m0 = tm * 8, n0 = tn * 4;

    float4 ra[4], rb[4], rc[4], rcb[4], rw[4];
    float acc[8][8];
    #pragma unroll
    for (int i = 0; i < 8; ++i)
        #pragma unroll
        for (int j = 0; j < 8; ++j) acc[i][j] = 0.f;

    auto g_load = [&](int s) {
        const int ob = s * KK + half * 16;
        #pragma unroll
        for (int p = 0; p < 4; ++p) {
            ra[p]  = *(const float4*)(r1 + ob + 4 * p);
            rb[p]  = *(const float4*)(r0 + ob + 4 * p);
            rc[p]  = *(const float4*)(r2 + ob + 4 * p);
            rcb[p] = *(const float4*)(cb + ob + 4 * p);
        }
        const float* ws = wbase + (size_t)s * KK * H2 * JD;
        #pragma unroll
        for (int p = 0; p < 4; ++p)
            rw[p] = *(const float4*)(ws + (size_t)4 * p);
    };

    auto lds_write = [&](int buf) {
        #pragma unroll
        for (int p = 0; p < 4; ++p) {
            int kk = half * 16 + 4 * p;
            Yt[buf][kk + 0][m] = ra[p].x + rb[p].x + rc[p].x + rcb[p].x;
            Yt[buf][kk + 1][m] = ra[p].y + rb[p].y + rc[p].y + rcb[p].y;
            Yt[buf][kk + 2][m] = ra[p].z + rb[p].z + rc[p].z + rcb[p].z;
            Yt[buf][kk + 3][m] = ra[p].w + rb[p].w + rc[p].w + rcb[p].w;
            *(float4*)&Wt[buf][wrow][wcol + 4 * p] = rw[p];
        }
    };

    auto fma_tile = [&](int buf) {
        #pragma unroll 4
        for (int kk = 0; kk < KK; ++kk) {
            float4 ya = *(const float4*)&Yt[buf][kk][m0];
            float4 yb = *(const float4*)&Yt[buf][kk][m0 + 4];
            float4 wa = *(const float4*)&Wt[buf][kk][n0];
            float4 wb = *(const float4*)&Wt[buf][kk][n0 + 64];
            float ys[8]  = {ya.x, ya.y, ya.z, ya.w, yb.x, yb.y, yb.z, yb.w};
            float wsv[8] = {wa.x, wa.y, wa.z, wa.w, wb.x, wb.y, wb.z, wb.w};
            #pragma unroll
            for (int r = 0; r < 8; ++r)
                #pragma unroll
                for (int c = 0; c < 8; ++c)
                    acc[r][c] = fmaf(ys[r], wsv[c], acc[r][c]);
        }
    };

    // --- pipelined main loop: 8 stages of 32 o's
    g_load(0);
    lds_write(0);
    __syncthreads();
    int cur = 0;
    for (int s = 0; s < 8; ++s) {
        if (s < 7) g_load(s + 1);          // global loads overlap FMA
        fma_tile(cur);
        if (s < 7) lds_write(cur ^ 1);     // waits vmem, writes other buffer
        __syncthreads();
        cur ^= 1;
    }

    // --- epilogue: partial[h][b0+m][j]
    const size_t orow = ((size_t)h * BB + b0);
    #pragma unroll
    for (int r = 0; r < 8; ++r) {
        float* dst = partial + (orow + m0 + r) * JD;
        *(float4*)(dst + n0)      = make_float4(acc[r][0], acc[r][1], acc[r][2], acc[r][3]);
        *(float4*)(dst + n0 + 64) = make_float4(acc[r][4], acc[r][5], acc[r][6], acc[r][7]);
    }
}

// ---------- reduce partials over h + bias (+ optional row softmax) ----------
template <int DO_SM>
__global__ void k_reduce(const float* __restrict__ partial, const float* __restrict__ bias,
                         float* __restrict__ outp) {
    int b = blockIdx.x;
    int j = threadIdx.x;  // 128
    float s = bias[j];
    for (int h = 0; h < H2; h++)
        s += partial[((size_t)h * BB + b) * JD + j];
    if (DO_SM) {
        __shared__ float red[JD];
        red[j] = s;
        __syncthreads();
        for (int st = 64; st > 0; st >>= 1) {
            if (j < st) red[j] = fmaxf(red[j], red[j + st]);
            __syncthreads();
        }
        float mx = red[0];
        __syncthreads();
        float e = expf(s - mx);
        red[j] = e;
        __syncthreads();
        for (int st = 64; st > 0; st >>= 1) {
            if (j < st) red[j] += red[j + st];
            __syncthreads();
        }
        outp[(size_t)b * JD + j] = e / red[0];
    } else {
        outp[(size_t)b * JD + j] = s;
    }
}

// ---------- manip conv values ----------
__global__ void k_mvals(const float* __restrict__ eo, const float* __restrict__ Wc,
                        const float* __restrict__ mcb, float* __restrict__ m3) {
    int idx = blockIdx.x * blockDim.x + threadIdx.x;  // 3*256*64
    int o = idx & 63;
    int b = (idx >> 6) & 255;
    int cls = idx >> 14;
    float acc = mcb[o];
    const float* w = Wc + (size_t)(cls * 128) * 64 + o;
    const float* e = eo + (size_t)b * JD;
    for (int i = 0; i < 128; i++) acc += e[i] * w[(size_t)i * 64];
    m3[idx] = fmaxf(acc, 0.f);
}

// ---------- manip linear + token quantization ----------
__global__ void k_m2tok(const float* __restrict__ m3, const float* __restrict__ mlw,
                        const float* __restrict__ Lint, const float* __restrict__ mlb,
                        int* __restrict__ tokens) {
    int j = threadIdx.x;   // 256
    int b = blockIdx.x;    // 256
    float acc = mlb[j];
    const float* m0p = m3 + (size_t)(0 * BB + b) * MO;
    const float* mip = m3 + (size_t)(1 * BB + b) * MO;
    const float* m1p = m3 + (size_t)(2 * BB + b) * MO;
    for (int o = 0; o < MO; o++) {
        acc += m0p[o] * mlw[((size_t)(o * H2 + 0)) * MJ + j];
        acc += mip[o] * Lint[(size_t)o * MJ + j];
        acc += m1p[o] * mlw[((size_t)(o * H2 + 127)) * MJ + j];
    }
    int t = ((int)floorf(fabsf(acc) * 100.f)) % NV;
    tokens[(size_t)b * LL + j] = t;
}

// ---------- final: f1 @ lin2 + b2, row softmax over 14 ----------
__global__ void k_final(const float* __restrict__ f1, const float* __restrict__ fl2,
                        const float* __restrict__ fb2, float* __restrict__ outp) {
    int b = blockIdx.x;
    int v = threadIdx.x;  // 64
    __shared__ float sl[NV];
    if (v < NV) {
        float acc = fb2[v];
        const float* fr = f1 + (size_t)b * JD;
        for (int jj = 0; jj < JD; jj++) acc += fr[jj] * fl2[(size_t)jj * NV + v];
        sl[v] = acc;
    }
    __syncthreads();
    if (v < NV) {
        float mx = -1e30f;
        for (int u = 0; u < NV; u++) mx = fmaxf(mx, sl[u]);
        float s = 0.f;
        for (int u = 0; u < NV; u++) s += expf(sl[u] - mx);
        outp[(size_t)b * NV + v] = expf(sl[v] - mx) / s;
    }
}

extern "C" void kernel_launch(void* const* d_in, const int* in_sizes, int n_in,
                              void* d_out, int out_size, void* d_ws, size_t ws_size,
                              hipStream_t stream) {
    const int*   x    = (const int*)d_in[0];
    const float* eemb = (const float*)d_in[1];
    const float* ecw  = (const float*)d_in[2];
    const float* ecb  = (const float*)d_in[3];
    const float* elw  = (const float*)d_in[4];
    const float* elb  = (const float*)d_in[5];
    // d_in[6] rand_proj: provably unused (fog_of_war returns identity permutation)
    const float* mcw  = (const float*)d_in[7];
    const float* mcb  = (const float*)d_in[8];
    const float* mlw  = (const float*)d_in[9];
    const float* mlb  = (const float*)d_in[10];
    const float* femb = (const float*)d_in[11];
    const float* fcw  = (const float*)d_in[12];
    const float* fcb  = (const float*)d_in[13];
    const float* flw1 = (const float*)d_in[14];
    const float* flb1 = (const float*)d_in[15];
    const float* fl2  = (const float*)d_in[16];
    const float* fb2  = (const float*)d_in[17];
    float* outp = (float*)d_out;

    char* w = (char*)d_ws;
    size_t off = 0;
    auto alloc = [&](size_t bytes) {
        void* p = w + off;
        off = (off + bytes + 255) & ~(size_t)255;
        return p;
    };
    float* P      = (float*)alloc(2ull * NP * EMBD * 4);        // 0.8 MB
    float* cwT    = (float*)alloc(2ull * 3 * EMBD * OC * 4);    // 3.1 MB
    float* C      = (float*)alloc(2ull * NP * 3 * OC * 4);      // 1.2 MB
    float* Czero  = (float*)alloc(256ull * 4);
    float* Wc     = (float*)alloc(3ull * 128 * 64 * 4);
    float* Lint   = (float*)alloc(64ull * MJ * 4);
    float* eo     = (float*)alloc((size_t)BB * JD * 4);
    float* m3     = (float*)alloc(3ull * BB * MO * 4);
    int*   tokens = (int*)alloc((size_t)BB * LL * 4);
    float* f1     = (float*)alloc((size_t)BB * JD * 4);
    float* partial= (float*)alloc((size_t)H2 * BB * JD * 4);    // 16.8 MB

    const float* C_e = C;
    const float* C_f = C + (size_t)NP * 3 * OC;

    // ---- b-independent precomputation ----
    (void)hipMemsetAsync(Czero, 0, 256 * 4, stream);
    k_pairs<<<2 * NP, 256, 0, stream>>>(eemb, femb, P);
    k_cwt<<<(2 * 3 * EMBD * OC) / 256, 256, 0, stream>>>(ecw, fcw, cwT);
    k_manipw<<<(3 * 128 * 64) / 256, 256, 0, stream>>>(mcw, Wc);
    k_lint<<<(64 * MJ) / 256, 256, 0, stream>>>(mlw, Lint);
    k_contrib<<<2 * 3 * 28, 256, 0, stream>>>(P, cwT, C);

    // ---- enemy branch: fused assembly+GEMM, then reduce+softmax ----
    k_branch_gemm<<<dim3(H2, 2), 256, 0, stream>>>(x, C_e, Czero, ecb, elw, partial);
    k_reduce<1><<<BB, JD, 0, stream>>>(partial, elb, eo);   // softmax -> enemy_out

    // ---- manipulator + token quantization ----
    k_mvals<<<(3 * BB * MO) / 256, 256, 0, stream>>>(eo, Wc, mcb, m3);
    k_m2tok<<<BB, MJ, 0, stream>>>(m3, mlw, Lint, mlb, tokens);

    // ---- friend branch ----
    k_branch_gemm<<<dim3(H2, 2), 256, 0, stream>>>(tokens, C_f, Czero, fcb, flw1, partial);
    k_reduce<0><<<BB, JD, 0, stream>>>(partial, flb1, f1);

    // ---- head ----
    k_final<<<BB, 64, 0, stream>>>(f1, fl2, fb2, outp);
}

// Round 4
// 127.473 us; speedup vs baseline: 3.7088x; 1.4744x over previous
//
#include <hip/hip_runtime.h>
#include <hip/hip_bf16.h>
#include <math.h>

#define BB    256   // batch
#define LL    256   // seq len
#define NV    14    // vocab
#define EMBD  512
#define H2    128   // L//2
#define OC    256   // branch conv out channels
#define NP    196   // 14*14 ordered token pairs
#define JD    128   // branch linear out
#define MO    64    // manip conv out channels
#define MJ    256   // manip linear out

using s16x8 = __attribute__((ext_vector_type(8))) short;
using f32x4 = __attribute__((ext_vector_type(4))) float;

static __device__ __forceinline__ unsigned short f2bf_rne(float f) {
    unsigned int u = __float_as_uint(f);
    unsigned int r = (u + 0x7FFFu + ((u >> 16) & 1u)) >> 16;
    return (unsigned short)r;
}
static __device__ __forceinline__ float bf2f(unsigned short h) {
    return __uint_as_float(((unsigned int)h) << 16);
}

// ---------- combined prep: pairs | cwt | manipw | lint by blockIdx range ----------
__global__ void k_prep(const float* __restrict__ emb_e, const float* __restrict__ emb_f,
                       const float* __restrict__ cw_e, const float* __restrict__ cw_f,
                       const float* __restrict__ mcw, const float* __restrict__ mlw,
                       float* __restrict__ P, float* __restrict__ cwT,
                       float* __restrict__ Wc, float* __restrict__ Lint) {
    int bid = blockIdx.x;
    int t = threadIdx.x;
    if (bid < 392) {                       // pairs: P[br][q][c]
        int q = bid % NP, br = bid / NP;
        const float* emb = br ? emb_f : emb_e;
        int t1 = q / NV, t2 = q % NV;
        float* outp = P + ((size_t)br * NP + q) * EMBD;
        for (int c = t; c < EMBD; c += 256)
            outp[c] = fmaxf(emb[t1 * EMBD + c], emb[t2 * EMBD + c]);
    } else if (bid < 392 + 3072) {         // cwt: cwT[br][kh][i][o]
        int idx = (bid - 392) * 256 + t;
        int o = idx & 255;
        int i = (idx >> 8) & 511;
        int rest = idx >> 17;
        int kh = rest % 3, br = rest / 3;
        const float* cw = br ? cw_f : cw_e;
        cwT[idx] = cw[((size_t)(o * EMBD + i) * 3 + kh) * 3 + 1];
    } else if (bid < 392 + 3072 + 96) {    // manipw
        int idx = (bid - 392 - 3072) * 256 + t;
        int o = idx & 63;
        int i = (idx >> 6) & 127;
        int cls = idx >> 13;
        const float* base = mcw + ((size_t)(o * 128 + i) * 3) * 3 + 1;
        float v = 0.f;
        if (cls != 2) { v += base[3]; v += base[6]; }
        else          { v += base[0]; v += base[3]; }
        if (cls == 1)   v += base[0];
        Wc[idx] = v;
    } else {                                // lint
        int idx = (bid - 392 - 3072 - 96) * 256 + t;
        int j = idx & 255;
        int o = idx >> 8;
        float s = 0.f;
        for (int h = 1; h <= 126; h++)
            s += mlw[((size_t)(o * H2 + h)) * MJ + j];
        Lint[idx] = s;
    }
}

// ---------- pair contributions: C[br][q][kh][o]; cb folded into kh==1 row ----------
__global__ void k_contrib(const float* __restrict__ P, const float* __restrict__ cwT,
                          const float* __restrict__ cb_e, const float* __restrict__ cb_f,
                          float* __restrict__ C) {
    int bid = blockIdx.x;         // 2*3*28
    int qg = bid % 28;
    int kh = (bid / 28) % 3;
    int br = bid / 84;
    int o = threadIdx.x;
    const float* w  = cwT + ((size_t)(br * 3 + kh) * EMBD) * OC + o;
    const float* Pb = P + ((size_t)br * NP + qg * 7) * EMBD;
    float acc[7];
    #pragma unroll
    for (int qq = 0; qq < 7; qq++) acc[qq] = 0.f;
    for (int i = 0; i < EMBD; i++) {
        float wv = w[(size_t)i * OC];
        #pragma unroll
        for (int qq = 0; qq < 7; qq++) acc[qq] += wv * Pb[(size_t)qq * EMBD + i];
    }
    float cbv = (kh == 1) ? (br ? cb_f[o] : cb_e[o]) : 0.f;
    #pragma unroll
    for (int qq = 0; qq < 7; qq++)
        C[(((size_t)br * NP + qg * 7 + qq) * 3 + kh) * OC + o] = acc[qq] + cbv;
}

// ---------- MFMA GEMM: partial[h][b][j] = sum_o Y[b,h,o]*lw[(o*H2+h)*JD+j] ----------
// Y assembled on the fly from C rows (gathered by tokens). X3=1: bf16 hi/lo
// 3-product split (near-fp32); X3=0: plain bf16.
// grid (128 h, 2 mt), 512 threads = 8 waves (2 Wm x 4 Wn), block tile 128m x 128n,
// K=256 in 8 stages of 32 (one mfma-K per stage), double-buffered LDS.
template <int X3>
__global__ __launch_bounds__(512) void k_gemm(
        const int* __restrict__ tok, const float* __restrict__ C,
        const float* __restrict__ lw, float* __restrict__ partial) {
    __shared__ unsigned short Ah[2][128][36];
    __shared__ unsigned short Al[2][128][36];
    __shared__ unsigned short Bh[2][128][36];
    __shared__ unsigned short Bl[2][128][36];

    const int h  = blockIdx.x;
    const int B0 = blockIdx.y * 128;
    const int t  = threadIdx.x;

    // ---- A gather setup (thread: row am, k-quad kq)
    const int am = t >> 2;
    const int kq = (t & 3) * 8;
    const int* tb = tok + (size_t)(B0 + am) * LL;
    const int q1 = tb[2 * h] * NV + tb[2 * h + 1];
    const float* r1 = C + ((size_t)q1 * 3 + 1) * OC + kq;
    const float* r0 = nullptr;
    const float* r2 = nullptr;
    if (h > 0)      { int q0 = tb[2 * h - 2] * NV + tb[2 * h - 1]; r0 = C + ((size_t)q0 * 3 + 0) * OC + kq; }
    if (h < H2 - 1) { int q2 = tb[2 * h + 2] * NV + tb[2 * h + 3]; r2 = C + ((size_t)q2 * 3 + 2) * OC + kq; }

    // ---- B setup (thread: k-row ko, 8 j's at j0)
    const int ko = t & 31;
    const int j0 = (t >> 5) * 8;
    const float* wsrc = lw + ((size_t)ko * H2 + h) * JD + j0;

    float4 ya0, ya1, yb0, yb1, yc0, yc1, wv0, wv1;

    auto load = [&](int s) {
        const float* p1 = r1 + s * 32;
        ya0 = *(const float4*)(p1);
        ya1 = *(const float4*)(p1 + 4);
        if (r0) { const float* p0 = r0 + s * 32; yb0 = *(const float4*)(p0); yb1 = *(const float4*)(p0 + 4); }
        else    { yb0 = make_float4(0, 0, 0, 0); yb1 = yb0; }
        if (r2) { const float* p2 = r2 + s * 32; yc0 = *(const float4*)(p2); yc1 = *(const float4*)(p2 + 4); }
        else    { yc0 = make_float4(0, 0, 0, 0); yc1 = yc0; }
        const float* pw = wsrc + (size_t)s * 32 * H2 * JD;
        wv0 = *(const float4*)(pw);
        wv1 = *(const float4*)(pw + 4);
    };

    auto store = [&](int buf) {
        float y[8];
        y[0] = ya0.x + yb0.x + yc0.x; y[1] = ya0.y + yb0.y + yc0.y;
        y[2] = ya0.z + yb0.z + yc0.z; y[3] = ya0.w + yb0.w + yc0.w;
        y[4] = ya1.x + yb1.x + yc1.x; y[5] = ya1.y + yb1.y + yc1.y;
        y[6] = ya1.z + yb1.z + yc1.z; y[7] = ya1.w + yb1.w + yc1.w;
        unsigned short hi[8];
        #pragma unroll
        for (int e = 0; e < 8; ++e) hi[e] = f2bf_rne(y[e]);
        uint2 u0, u1;
        u0.x = (unsigned)hi[0] | ((unsigned)hi[1] << 16);
        u0.y = (unsigned)hi[2] | ((unsigned)hi[3] << 16);
        u1.x = (unsigned)hi[4] | ((unsigned)hi[5] << 16);
        u1.y = (unsigned)hi[6] | ((unsigned)hi[7] << 16);
        *(uint2*)&Ah[buf][am][kq]     = u0;
        *(uint2*)&Ah[buf][am][kq + 4] = u1;
        if (X3) {
            unsigned short lo[8];
            #pragma unroll
            for (int e = 0; e < 8; ++e) lo[e] = f2bf_rne(y[e] - bf2f(hi[e]));
            uint2 v0, v1;
            v0.x = (unsigned)lo[0] | ((unsigned)lo[1] << 16);
            v0.y = (unsigned)lo[2] | ((unsigned)lo[3] << 16);
            v1.x = (unsigned)lo[4] | ((unsigned)lo[5] << 16);
            v1.y = (unsigned)lo[6] | ((unsigned)lo[7] << 16);
            *(uint2*)&Al[buf][am][kq]     = v0;
            *(uint2*)&Al[buf][am][kq + 4] = v1;
        }
        float wv[8] = {wv0.x, wv0.y, wv0.z, wv0.w, wv1.x, wv1.y, wv1.z, wv1.w};
        #pragma unroll
        for (int e = 0; e < 8; ++e) {
            unsigned short wh = f2bf_rne(wv[e]);
            Bh[buf][j0 + e][ko] = wh;
            if (X3) Bl[buf][j0 + e][ko] = f2bf_rne(wv[e] - bf2f(wh));
        }
    };

    // ---- compute mapping
    const int lane = t & 63, wid = t >> 6;
    const int Wm = (wid >> 2) * 64;     // 0 or 64
    const int Wn = (wid & 3) * 32;      // 0,32,64,96
    const int fr = lane & 15;
    const int g8 = (lane >> 4) * 8;

    f32x4 acc[4][2] = {};

    auto rd8 = [&](const unsigned short* p) -> s16x8 {
        union { s16x8 v; uint2 u[2]; } tmp;
        tmp.u[0] = *(const uint2*)(p);
        tmp.u[1] = *(const uint2*)(p + 4);
        return tmp.v;
    };

    auto compute = [&](int buf) {
        s16x8 a_h[4], b_h[2];
        #pragma unroll
        for (int mf = 0; mf < 4; ++mf) a_h[mf] = rd8(&Ah[buf][Wm + mf * 16 + fr][g8]);
        #pragma unroll
        for (int nf = 0; nf < 2; ++nf) b_h[nf] = rd8(&Bh[buf][Wn + nf * 16 + fr][g8]);
        #pragma unroll
        for (int mf = 0; mf < 4; ++mf)
            #pragma unroll
            for (int nf = 0; nf < 2; ++nf)
                acc[mf][nf] = __builtin_amdgcn_mfma_f32_16x16x32_bf16(a_h[mf], b_h[nf], acc[mf][nf], 0, 0, 0);
        if (X3) {
            s16x8 a_l[4], b_l[2];
            #pragma unroll
            for (int mf = 0; mf < 4; ++mf) a_l[mf] = rd8(&Al[buf][Wm + mf * 16 + fr][g8]);
            #pragma unroll
            for (int nf = 0; nf < 2; ++nf) b_l[nf] = rd8(&Bl[buf][Wn + nf * 16 + fr][g8]);
            #pragma unroll
            for (int mf = 0; mf < 4; ++mf)
                #pragma unroll
                for (int nf = 0; nf < 2; ++nf) {
                    acc[mf][nf] = __builtin_amdgcn_mfma_f32_16x16x32_bf16(a_h[mf], b_l[nf], acc[mf][nf], 0, 0, 0);
                    acc[mf][nf] = __builtin_amdgcn_mfma_f32_16x16x32_bf16(a_l[mf], b_h[nf], acc[mf][nf], 0, 0, 0);
                }
        }
    };

    // ---- main loop
    load(0);
    store(0);
    __syncthreads();
    for (int s = 0; s < 8; ++s) {
        if (s < 7) load(s + 1);
        compute(s & 1);
        if (s < 7) store((s + 1) & 1);
        __syncthreads();
    }

    // ---- epilogue: D mapping col=lane&15, row=4*(lane>>4)+reg
    float* pb = partial + ((size_t)h * BB + B0 + Wm) * JD + Wn;
    #pragma unroll
    for (int mf = 0; mf < 4; ++mf)
        #pragma unroll
        for (int nf = 0; nf < 2; ++nf)
            #pragma unroll
            for (int r = 0; r < 4; ++r) {
                int row = mf * 16 + (lane >> 4) * 4 + r;
                int col = nf * 16 + fr;
                pb[(size_t)row * JD + col] = acc[mf][nf][r];
            }
}

// ---------- fuse E: reduce + softmax + manip conv + manip linear + tokens ----------
__global__ __launch_bounds__(256) void k_fuseE(
        const float* __restrict__ partial, const float* __restrict__ elb,
        const float* __restrict__ Wc, const float* __restrict__ mcb,
        const float* __restrict__ mlw, const float* __restrict__ Lint,
        const float* __restrict__ mlb, int* __restrict__ tokens) {
    int b = blockIdx.x, t = threadIdx.x;
    __shared__ float S[2][128];
    __shared__ float eo[128];
    __shared__ float m3[3][64];
    __shared__ float red[128];

    int j = t & 127, hh = t >> 7;
    float s = 0.f;
    for (int h = hh * 64; h < hh * 64 + 64; ++h)
        s += partial[((size_t)h * BB + b) * JD + j];
    S[hh][j] = s;
    __syncthreads();
    if (t < 128) {
        float v = S[0][t] + S[1][t] + elb[t];
        S[0][t] = v;
        red[t] = v;
    }
    __syncthreads();
    for (int st = 64; st > 0; st >>= 1) {
        if (t < st) red[t] = fmaxf(red[t], red[t + st]);
        __syncthreads();
    }
    float mx = red[0];
    __syncthreads();
    if (t < 128) {
        float e = expf(S[0][t] - mx);
        eo[t] = e;
        red[t] = e;
    }
    __syncthreads();
    for (int st = 64; st > 0; st >>= 1) {
        if (t < st) red[t] += red[t + st];
        __syncthreads();
    }
    float inv = 1.f / red[0];
    __syncthreads();
    if (t < 128) eo[t] *= inv;
    __syncthreads();
    // manip conv values
    if (t < 192) {
        int cls = t >> 6, o = t & 63;
        float a = mcb[o];
        const float* wp = Wc + (size_t)cls * 128 * 64 + o;
        for (int i = 0; i < 128; ++i) a = fmaf(eo[i], wp[(size_t)i * 64], a);
        m3[cls][o] = fmaxf(a, 0.f);
    }
    __syncthreads();
    // manip linear + token quantization (t = j 0..255)
    float a = mlb[t];
    for (int o = 0; o < MO; ++o) {
        a = fmaf(m3[0][o], mlw[((size_t)(o * H2 + 0)) * MJ + t], a);
        a = fmaf(m3[1][o], Lint[(size_t)o * MJ + t], a);
        a = fmaf(m3[2][o], mlw[((size_t)(o * H2 + 127)) * MJ + t], a);
    }
    tokens[(size_t)b * LL + t] = ((int)floorf(fabsf(a) * 100.f)) % NV;
}

// ---------- fuse F: reduce + head linear + softmax(14) ----------
__global__ __launch_bounds__(256) void k_fuseF(
        const float* __restrict__ partial, const float* __restrict__ flb1,
        const float* __restrict__ fl2, const float* __restrict__ fb2,
        float* __restrict__ outp) {
    int b = blockIdx.x, t = threadIdx.x;
    __shared__ float S[2][128];
    __shared__ float f1[128];
    __shared__ float sl[NV];
    int j = t & 127, hh = t >> 7;
    float s = 0.f;
    for (int h = hh * 64; h < hh * 64 + 64; ++h)
        s += partial[((size_t)h * BB + b) * JD + j];
    S[hh][j] = s;
    __syncthreads();
    if (t < 128) f1[t] = S[0][t] + S[1][t] + flb1[t];
    __syncthreads();
    if (t < NV) {
        float a = fb2[t];
        for (int jj = 0; jj < 128; ++jj) a = fmaf(f1[jj], fl2[(size_t)jj * NV + t], a);
        sl[t] = a;
    }
    __syncthreads();
    if (t < NV) {
        float mx = -1e30f;
        for (int u = 0; u < NV; ++u) mx = fmaxf(mx, sl[u]);
        float ss = 0.f;
        for (int u = 0; u < NV; ++u) ss += expf(sl[u] - mx);
        outp[(size_t)b * NV + t] = expf(sl[t] - mx) / ss;
    }
}

extern "C" void kernel_launch(void* const* d_in, const int* in_sizes, int n_in,
                              void* d_out, int out_size, void* d_ws, size_t ws_size,
                              hipStream_t stream) {
    const int*   x    = (const int*)d_in[0];
    const float* eemb = (const float*)d_in[1];
    const float* ecw  = (const float*)d_in[2];
    const float* ecb  = (const float*)d_in[3];
    const float* elw  = (const float*)d_in[4];
    const float* elb  = (const float*)d_in[5];
    // d_in[6] rand_proj: provably unused (fog_of_war returns identity permutation)
    const float* mcw  = (const float*)d_in[7];
    const float* mcb  = (const float*)d_in[8];
    const float* mlw  = (const float*)d_in[9];
    const float* mlb  = (const float*)d_in[10];
    const float* femb = (const float*)d_in[11];
    const float* fcw  = (const float*)d_in[12];
    const float* fcb  = (const float*)d_in[13];
    const float* flw1 = (const float*)d_in[14];
    const float* flb1 = (const float*)d_in[15];
    const float* fl2  = (const float*)d_in[16];
    const float* fb2  = (const float*)d_in[17];
    float* outp = (float*)d_out;

    char* w = (char*)d_ws;
    size_t off = 0;
    auto alloc = [&](size_t bytes) {
        void* p = w + off;
        off = (off + bytes + 255) & ~(size_t)255;
        return p;
    };
    float* P      = (float*)alloc(2ull * NP * EMBD * 4);        // 0.8 MB
    float* cwT    = (float*)alloc(2ull * 3 * EMBD * OC * 4);    // 3.1 MB
    float* C      = (float*)alloc(2ull * NP * 3 * OC * 4);      // 1.2 MB
    float* Wc     = (float*)alloc(3ull * 128 * 64 * 4);
    float* Lint   = (float*)alloc(64ull * MJ * 4);
    int*   tokens = (int*)alloc((size_t)BB * LL * 4);
    float* partial= (float*)alloc((size_t)H2 * BB * JD * 4);    // 16.8 MB

    const float* C_e = C;
    const float* C_f = C + (size_t)NP * 3 * OC;

    // ---- prep (pairs | cwt | manipw | lint) ----
    k_prep<<<392 + 3072 + 96 + 64, 256, 0, stream>>>(eemb, femb, ecw, fcw, mcw, mlw,
                                                     P, cwT, Wc, Lint);
    k_contrib<<<2 * 3 * 28, 256, 0, stream>>>(P, cwT, ecb, fcb, C);

    // ---- enemy branch (bf16x3 MFMA — token path needs near-fp32) ----
    k_gemm<1><<<dim3(H2, 2), 512, 0, stream>>>(x, C_e, elw, partial);
    k_fuseE<<<BB, 256, 0, stream>>>(partial, elb, Wc, mcb, mlw, Lint, mlb, tokens);

    // ---- friend branch (plain bf16 MFMA) ----
    k_gemm<0><<<dim3(H2, 2), 512, 0, stream>>>(tokens, C_f, flw1, partial);
    k_fuseF<<<BB, 256, 0, stream>>>(partial, flb1, fl2, fb2, outp);
}

// Round 5
// 105.538 us; speedup vs baseline: 4.4797x; 1.2078x over previous
//
#include <hip/hip_runtime.h>
#include <hip/hip_bf16.h>
#include <math.h>

#define BB    256   // batch
#define LL    256   // seq len
#define NV    14    // vocab
#define EMBD  512
#define H2    128   // L//2
#define OC    256   // branch conv out channels
#define NP    196   // 14*14 ordered token pairs
#define JD    128   // branch linear out
#define MO    64    // manip conv out channels
#define MJ    256   // manip linear out

#define CROWS   (2 * NP * 3)            // C rows (br,q,kh)
#define CSTRIDE (CROWS * OC)            // 301056: one split-K slice of C
#define LINT4   (64 * 256)              // one lint partial slice

using s16x8 = __attribute__((ext_vector_type(8))) short;
using f32x4 = __attribute__((ext_vector_type(4))) float;

static __device__ __forceinline__ unsigned short f2bf_rne(float f) {
    unsigned int u = __float_as_uint(f);
    unsigned int r = (u + 0x7FFFu + ((u >> 16) & 1u)) >> 16;
    return (unsigned short)r;
}
static __device__ __forceinline__ float bf2f(unsigned short h) {
    return __uint_as_float(((unsigned int)h) << 16);
}

// ---------- combined prep: pairs | cwt | manipw | lint4 by blockIdx range ----------
__global__ void k_prep(const float* __restrict__ emb_e, const float* __restrict__ emb_f,
                       const float* __restrict__ cw_e, const float* __restrict__ cw_f,
                       const float* __restrict__ mcw, const float* __restrict__ mlw,
                       float* __restrict__ P, float* __restrict__ cwT,
                       float* __restrict__ Wc, float* __restrict__ Lint4) {
    int bid = blockIdx.x;
    int t = threadIdx.x;
    if (bid < 392) {                       // pairs: P[br][q][c]
        int q = bid % NP, br = bid / NP;
        const float* emb = br ? emb_f : emb_e;
        int t1 = q / NV, t2 = q % NV;
        float* outp = P + ((size_t)br * NP + q) * EMBD;
        for (int c = t; c < EMBD; c += 256)
            outp[c] = fmaxf(emb[t1 * EMBD + c], emb[t2 * EMBD + c]);
    } else if (bid < 392 + 3072) {         // cwt: cwT[br][kh][i][o]
        int idx = (bid - 392) * 256 + t;
        int o = idx & 255;
        int i = (idx >> 8) & 511;
        int rest = idx >> 17;
        int kh = rest % 3, br = rest / 3;
        const float* cw = br ? cw_f : cw_e;
        cwT[idx] = cw[((size_t)(o * EMBD + i) * 3 + kh) * 3 + 1];
    } else if (bid < 392 + 3072 + 96) {    // manipw
        int idx = (bid - 392 - 3072) * 256 + t;
        int o = idx & 63;
        int i = (idx >> 6) & 127;
        int cls = idx >> 13;
        const float* base = mcw + ((size_t)(o * 128 + i) * 3) * 3 + 1;
        float v = 0.f;
        if (cls != 2) { v += base[3]; v += base[6]; }
        else          { v += base[0]; v += base[3]; }
        if (cls == 1)   v += base[0];
        Wc[idx] = v;
    } else {                                // lint split-4 over h
        int lb = bid - (392 + 3072 + 96);   // 0..255
        int o = lb >> 2, hq = lb & 3;
        int h0 = hq * 32;
        int hs = h0 < 1 ? 1 : h0;
        int he = (h0 + 32) > 127 ? 127 : (h0 + 32);
        float s = 0.f;
        for (int h = hs; h < he; h++)
            s += mlw[((size_t)(o * H2 + h)) * MJ + t];
        Lint4[(size_t)hq * LINT4 + o * 256 + t] = s;
    }
}

// ---------- pair contributions, split-K x4: Cpart[ks][(br*NP+q)*3+kh][o] ----------
__global__ __launch_bounds__(256) void k_contrib(
        const float* __restrict__ P, const float* __restrict__ cwT,
        float* __restrict__ Cpart) {
    int bid = blockIdx.x;               // ((br*3+kh)*28+qg)*4+ks
    int ks = bid & 3;
    int qg = (bid >> 2) % 28;
    int kh = ((bid >> 2) / 28) % 3;
    int br = bid / (4 * 28 * 3);
    int o = threadIdx.x;

    __shared__ float Pl[7][128];
    for (int idx = o; idx < 7 * 128; idx += 256) {
        int row = idx >> 7, col = idx & 127;
        Pl[row][col] = P[((size_t)br * NP + qg * 7 + row) * EMBD + ks * 128 + col];
    }
    __syncthreads();

    const float* w = cwT + ((size_t)(br * 3 + kh) * EMBD + ks * 128) * OC + o;
    float acc[7];
    #pragma unroll
    for (int qq = 0; qq < 7; qq++) acc[qq] = 0.f;
    #pragma unroll 8
    for (int i = 0; i < 128; i++) {
        float wv = w[(size_t)i * OC];
        #pragma unroll
        for (int qq = 0; qq < 7; qq++) acc[qq] = fmaf(wv, Pl[qq][i], acc[qq]);
    }
    float* dst = Cpart + (size_t)ks * CSTRIDE + (((size_t)br * NP + qg * 7) * 3 + kh) * OC + o;
    #pragma unroll
    for (int qq = 0; qq < 7; qq++)
        dst[(size_t)qq * 3 * OC] = acc[qq];
}

// ---------- reduce Cpart (+ fold cb) and Lint4 ----------
__global__ __launch_bounds__(256) void k_cred(
        const float* __restrict__ Cpart, const float* __restrict__ cb_e,
        const float* __restrict__ cb_f, const float* __restrict__ Lint4,
        float* __restrict__ C, float* __restrict__ Lint) {
    int bid = blockIdx.x;
    int t = threadIdx.x;
    if (bid < CROWS) {                      // 1176 blocks: C reduce
        int idx = bid * 256 + t;
        float s = Cpart[idx] + Cpart[CSTRIDE + idx]
                + Cpart[2 * CSTRIDE + idx] + Cpart[3 * CSTRIDE + idx];
        int o = idx & 255;
        int kh = (idx >> 8) % 3;
        if (kh == 1) {
            int br = idx >= (NP * 3 * 256);
            s += br ? cb_f[o] : cb_e[o];
        }
        C[idx] = s;
    } else {                                 // 64 blocks: Lint reduce
        int idx = (bid - CROWS) * 256 + t;
        Lint[idx] = Lint4[idx] + Lint4[LINT4 + idx]
                  + Lint4[2 * LINT4 + idx] + Lint4[3 * LINT4 + idx];
    }
}

// ---------- MFMA GEMM: partial[h][b][j] = sum_o Y[b,h,o]*lw[(o*H2+h)*JD+j] ----------
template <int X3>
__global__ __launch_bounds__(512) void k_gemm(
        const int* __restrict__ tok, const float* __restrict__ C,
        const float* __restrict__ lw, float* __restrict__ partial) {
    __shared__ unsigned short Ah[2][128][36];
    __shared__ unsigned short Al[2][128][36];
    __shared__ unsigned short Bh[2][128][36];
    __shared__ unsigned short Bl[2][128][36];

    const int h  = blockIdx.x;
    const int B0 = blockIdx.y * 128;
    const int t  = threadIdx.x;

    // ---- A gather setup (thread: row am, k-quad kq)
    const int am = t >> 2;
    const int kq = (t & 3) * 8;
    const int* tb = tok + (size_t)(B0 + am) * LL;
    const int q1 = tb[2 * h] * NV + tb[2 * h + 1];
    const float* r1 = C + ((size_t)q1 * 3 + 1) * OC + kq;
    const float* r0 = nullptr;
    const float* r2 = nullptr;
    if (h > 0)      { int q0 = tb[2 * h - 2] * NV + tb[2 * h - 1]; r0 = C + ((size_t)q0 * 3 + 0) * OC + kq; }
    if (h < H2 - 1) { int q2 = tb[2 * h + 2] * NV + tb[2 * h + 3]; r2 = C + ((size_t)q2 * 3 + 2) * OC + kq; }

    // ---- B setup (thread: k-row ko, 8 j's at j0)
    const int ko = t & 31;
    const int j0 = (t >> 5) * 8;
    const float* wsrc = lw + ((size_t)ko * H2 + h) * JD + j0;

    float4 ya0, ya1, yb0, yb1, yc0, yc1, wv0, wv1;

    auto load = [&](int s) {
        const float* p1 = r1 + s * 32;
        ya0 = *(const float4*)(p1);
        ya1 = *(const float4*)(p1 + 4);
        if (r0) { const float* p0 = r0 + s * 32; yb0 = *(const float4*)(p0); yb1 = *(const float4*)(p0 + 4); }
        else    { yb0 = make_float4(0, 0, 0, 0); yb1 = yb0; }
        if (r2) { const float* p2 = r2 + s * 32; yc0 = *(const float4*)(p2); yc1 = *(const float4*)(p2 + 4); }
        else    { yc0 = make_float4(0, 0, 0, 0); yc1 = yc0; }
        const float* pw = wsrc + (size_t)s * 32 * H2 * JD;
        wv0 = *(const float4*)(pw);
        wv1 = *(const float4*)(pw + 4);
    };

    auto store = [&](int buf) {
        float y[8];
        y[0] = ya0.x + yb0.x + yc0.x; y[1] = ya0.y + yb0.y + yc0.y;
        y[2] = ya0.z + yb0.z + yc0.z; y[3] = ya0.w + yb0.w + yc0.w;
        y[4] = ya1.x + yb1.x + yc1.x; y[5] = ya1.y + yb1.y + yc1.y;
        y[6] = ya1.z + yb1.z + yc1.z; y[7] = ya1.w + yb1.w + yc1.w;
        unsigned short hi[8];
        #pragma unroll
        for (int e = 0; e < 8; ++e) hi[e] = f2bf_rne(y[e]);
        uint2 u0, u1;
        u0.x = (unsigned)hi[0] | ((unsigned)hi[1] << 16);
        u0.y = (unsigned)hi[2] | ((unsigned)hi[3] << 16);
        u1.x = (unsigned)hi[4] | ((unsigned)hi[5] << 16);
        u1.y = (unsigned)hi[6] | ((unsigned)hi[7] << 16);
        *(uint2*)&Ah[buf][am][kq]     = u0;
        *(uint2*)&Ah[buf][am][kq + 4] = u1;
        if (X3) {
            unsigned short lo[8];
            #pragma unroll
            for (int e = 0; e < 8; ++e) lo[e] = f2bf_rne(y[e] - bf2f(hi[e]));
            uint2 v0, v1;
            v0.x = (unsigned)lo[0] | ((unsigned)lo[1] << 16);
            v0.y = (unsigned)lo[2] | ((unsigned)lo[3] << 16);
            v1.x = (unsigned)lo[4] | ((unsigned)lo[5] << 16);
            v1.y = (unsigned)lo[6] | ((unsigned)lo[7] << 16);
            *(uint2*)&Al[buf][am][kq]     = v0;
            *(uint2*)&Al[buf][am][kq + 4] = v1;
        }
        float wv[8] = {wv0.x, wv0.y, wv0.z, wv0.w, wv1.x, wv1.y, wv1.z, wv1.w};
        #pragma unroll
        for (int e = 0; e < 8; ++e) {
            unsigned short wh = f2bf_rne(wv[e]);
            Bh[buf][j0 + e][ko] = wh;
            if (X3) Bl[buf][j0 + e][ko] = f2bf_rne(wv[e] - bf2f(wh));
        }
    };

    // ---- compute mapping
    const int lane = t & 63, wid = t >> 6;
    const int Wm = (wid >> 2) * 64;     // 0 or 64
    const int Wn = (wid & 3) * 32;      // 0,32,64,96
    const int fr = lane & 15;
    const int g8 = (lane >> 4) * 8;

    f32x4 acc[4][2] = {};

    auto rd8 = [&](const unsigned short* p) -> s16x8 {
        union { s16x8 v; uint2 u[2]; } tmp;
        tmp.u[0] = *(const uint2*)(p);
        tmp.u[1] = *(const uint2*)(p + 4);
        return tmp.v;
    };

    auto compute = [&](int buf) {
        s16x8 a_h[4], b_h[2];
        #pragma unroll
        for (int mf = 0; mf < 4; ++mf) a_h[mf] = rd8(&Ah[buf][Wm + mf * 16 + fr][g8]);
        #pragma unroll
        for (int nf = 0; nf < 2; ++nf) b_h[nf] = rd8(&Bh[buf][Wn + nf * 16 + fr][g8]);
        #pragma unroll
        for (int mf = 0; mf < 4; ++mf)
            #pragma unroll
            for (int nf = 0; nf < 2; ++nf)
                acc[mf][nf] = __builtin_amdgcn_mfma_f32_16x16x32_bf16(a_h[mf], b_h[nf], acc[mf][nf], 0, 0, 0);
        if (X3) {
            s16x8 a_l[4], b_l[2];
            #pragma unroll
            for (int mf = 0; mf < 4; ++mf) a_l[mf] = rd8(&Al[buf][Wm + mf * 16 + fr][g8]);
            #pragma unroll
            for (int nf = 0; nf < 2; ++nf) b_l[nf] = rd8(&Bl[buf][Wn + nf * 16 + fr][g8]);
            #pragma unroll
            for (int mf = 0; mf < 4; ++mf)
                #pragma unroll
                for (int nf = 0; nf < 2; ++nf) {
                    acc[mf][nf] = __builtin_amdgcn_mfma_f32_16x16x32_bf16(a_h[mf], b_l[nf], acc[mf][nf], 0, 0, 0);
                    acc[mf][nf] = __builtin_amdgcn_mfma_f32_16x16x32_bf16(a_l[mf], b_h[nf], acc[mf][nf], 0, 0, 0);
                }
        }
    };

    // ---- main loop
    load(0);
    store(0);
    __syncthreads();
    for (int s = 0; s < 8; ++s) {
        if (s < 7) load(s + 1);
        compute(s & 1);
        if (s < 7) store((s + 1) & 1);
        __syncthreads();
    }

    // ---- epilogue: D mapping col=lane&15, row=4*(lane>>4)+reg
    float* pb = partial + ((size_t)h * BB + B0 + Wm) * JD + Wn;
    #pragma unroll
    for (int mf = 0; mf < 4; ++mf)
        #pragma unroll
        for (int nf = 0; nf < 2; ++nf)
            #pragma unroll
            for (int r = 0; r < 4; ++r) {
                int row = mf * 16 + (lane >> 4) * 4 + r;
                int col = nf * 16 + fr;
                pb[(size_t)row * JD + col] = acc[mf][nf][r];
            }
}

// ---------- fuse E: reduce + softmax + manip conv + manip linear + tokens ----------
__global__ __launch_bounds__(256) void k_fuseE(
        const float* __restrict__ partial, const float* __restrict__ elb,
        const float* __restrict__ Wc, const float* __restrict__ mcb,
        const float* __restrict__ mlw, const float* __restrict__ Lint,
        const float* __restrict__ mlb, int* __restrict__ tokens) {
    int b = blockIdx.x, t = threadIdx.x;
    __shared__ float S[2][128];
    __shared__ float eo[128];
    __shared__ float m3[3][64];
    __shared__ float red[128];

    int j = t & 127, hh = t >> 7;
    float s = 0.f;
    for (int h = hh * 64; h < hh * 64 + 64; ++h)
        s += partial[((size_t)h * BB + b) * JD + j];
    S[hh][j] = s;
    __syncthreads();
    if (t < 128) {
        float v = S[0][t] + S[1][t] + elb[t];
        S[0][t] = v;
        red[t] = v;
    }
    __syncthreads();
    for (int st = 64; st > 0; st >>= 1) {
        if (t < st) red[t] = fmaxf(red[t], red[t + st]);
        __syncthreads();
    }
    float mx = red[0];
    __syncthreads();
    if (t < 128) {
        float e = expf(S[0][t] - mx);
        eo[t] = e;
        red[t] = e;
    }
    __syncthreads();
    for (int st = 64; st > 0; st >>= 1) {
        if (t < st) red[t] += red[t + st];
        __syncthreads();
    }
    float inv = 1.f / red[0];
    __syncthreads();
    if (t < 128) eo[t] *= inv;
    __syncthreads();
    // manip conv values
    if (t < 192) {
        int cls = t >> 6, o = t & 63;
        float a = mcb[o];
        const float* wp = Wc + (size_t)cls * 128 * 64 + o;
        for (int i = 0; i < 128; ++i) a = fmaf(eo[i], wp[(size_t)i * 64], a);
        m3[cls][o] = fmaxf(a, 0.f);
    }
    __syncthreads();
    // manip linear + token quantization (t = j 0..255)
    float a = mlb[t];
    for (int o = 0; o < MO; ++o) {
        a = fmaf(m3[0][o], mlw[((size_t)(o * H2 + 0)) * MJ + t], a);
        a = fmaf(m3[1][o], Lint[(size_t)o * MJ + t], a);
        a = fmaf(m3[2][o], mlw[((size_t)(o * H2 + 127)) * MJ + t], a);
    }
    tokens[(size_t)b * LL + t] = ((int)floorf(fabsf(a) * 100.f)) % NV;
}

// ---------- fuse F: reduce + head linear + softmax(14) ----------
__global__ __launch_bounds__(256) void k_fuseF(
        const float* __restrict__ partial, const float* __restrict__ flb1,
        const float* __restrict__ fl2, const float* __restrict__ fb2,
        float* __restrict__ outp) {
    int b = blockIdx.x, t = threadIdx.x;
    __shared__ float S[2][128];
    __shared__ float f1[128];
    __shared__ float sl[NV];
    int j = t & 127, hh = t >> 7;
    float s = 0.f;
    for (int h = hh * 64; h < hh * 64 + 64; ++h)
        s += partial[((size_t)h * BB + b) * JD + j];
    S[hh][j] = s;
    __syncthreads();
    if (t < 128) f1[t] = S[0][t] + S[1][t] + flb1[t];
    __syncthreads();
    if (t < NV) {
        float a = fb2[t];
        for (int jj = 0; jj < 128; ++jj) a = fmaf(f1[jj], fl2[(size_t)jj * NV + t], a);
        sl[t] = a;
    }
    __syncthreads();
    if (t < NV) {
        float mx = -1e30f;
        for (int u = 0; u < NV; ++u) mx = fmaxf(mx, sl[u]);
        float ss = 0.f;
        for (int u = 0; u < NV; ++u) ss += expf(sl[u] - mx);
        outp[(size_t)b * NV + t] = expf(sl[t] - mx) / ss;
    }
}

extern "C" void kernel_launch(void* const* d_in, const int* in_sizes, int n_in,
                              void* d_out, int out_size, void* d_ws, size_t ws_size,
                              hipStream_t stream) {
    const int*   x    = (const int*)d_in[0];
    const float* eemb = (const float*)d_in[1];
    const float* ecw  = (const float*)d_in[2];
    const float* ecb  = (const float*)d_in[3];
    const float* elw  = (const float*)d_in[4];
    const float* elb  = (const float*)d_in[5];
    // d_in[6] rand_proj: provably unused (fog_of_war returns identity permutation)
    const float* mcw  = (const float*)d_in[7];
    const float* mcb  = (const float*)d_in[8];
    const float* mlw  = (const float*)d_in[9];
    const float* mlb  = (const float*)d_in[10];
    const float* femb = (const float*)d_in[11];
    const float* fcw  = (const float*)d_in[12];
    const float* fcb  = (const float*)d_in[13];
    const float* flw1 = (const float*)d_in[14];
    const float* flb1 = (const float*)d_in[15];
    const float* fl2  = (const float*)d_in[16];
    const float* fb2  = (const float*)d_in[17];
    float* outp = (float*)d_out;

    char* w = (char*)d_ws;
    size_t off = 0;
    auto alloc = [&](size_t bytes) {
        void* p = w + off;
        off = (off + bytes + 255) & ~(size_t)255;
        return p;
    };
    float* P      = (float*)alloc(2ull * NP * EMBD * 4);        // 0.8 MB
    float* cwT    = (float*)alloc(2ull * 3 * EMBD * OC * 4);    // 3.1 MB
    float* C      = (float*)alloc((size_t)CSTRIDE * 4);         // 1.2 MB
    float* Cpart  = (float*)alloc(4ull * CSTRIDE * 4);          // 4.8 MB
    float* Wc     = (float*)alloc(3ull * 128 * 64 * 4);
    float* Lint   = (float*)alloc(64ull * MJ * 4);
    float* Lint4  = (float*)alloc(4ull * LINT4 * 4);            // 0.25 MB
    int*   tokens = (int*)alloc((size_t)BB * LL * 4);
    float* partial= (float*)alloc((size_t)H2 * BB * JD * 4);    // 16.8 MB

    const float* C_e = C;
    const float* C_f = C + (size_t)NP * 3 * OC;

    // ---- prep (pairs | cwt | manipw | lint4) ----
    k_prep<<<392 + 3072 + 96 + 256, 256, 0, stream>>>(eemb, femb, ecw, fcw, mcw, mlw,
                                                      P, cwT, Wc, Lint4);
    // ---- pair contributions (split-K x4) + reduce ----
    k_contrib<<<2 * 3 * 28 * 4, 256, 0, stream>>>(P, cwT, Cpart);
    k_cred<<<CROWS + 64, 256, 0, stream>>>(Cpart, ecb, fcb, Lint4, C, Lint);

    // ---- enemy branch (bf16x3 MFMA — token path needs near-fp32) ----
    k_gemm<1><<<dim3(H2, 2), 512, 0, stream>>>(x, C_e, elw, partial);
    k_fuseE<<<BB, 256, 0, stream>>>(partial, elb, Wc, mcb, mlw, Lint, mlb, tokens);

    // ---- friend branch (plain bf16 MFMA) ----
    k_gemm<0><<<dim3(H2, 2), 512, 0, stream>>>(tokens, C_f, flw1, partial);
    k_fuseF<<<BB, 256, 0, stream>>>(partial, flb1, fl2, fb2, outp);
}

// Round 6
// 99.981 us; speedup vs baseline: 4.7287x; 1.0556x over previous
//
#include <hip/hip_runtime.h>
#include <hip/hip_bf16.h>
#include <math.h>

#define BB    256   // batch
#define LL    256   // seq len
#define NV    14    // vocab
#define EMBD  512
#define H2    128   // L//2
#define OC    256   // branch conv out channels
#define NP    196   // 14*14 ordered token pairs
#define JD    128   // branch linear out
#define MO    64    // manip conv out channels
#define MJ    256   // manip linear out

#define CROWS   (2 * NP * 3)            // C rows (br,q,kh)
#define CSTRIDE (CROWS * OC)            // 301056: one split-K slice of C
#define LINT4   (64 * 256)              // one lint partial slice

// prep block ranges
#define PB_PAIRS  392
#define PB_CWT    256                   // 2 br * 4 o-chunks * 32 i-chunks
#define PB_MANIPW 96
#define PB_LINT   256

using s16x8 = __attribute__((ext_vector_type(8))) short;
using f32x4 = __attribute__((ext_vector_type(4))) float;

static __device__ __forceinline__ unsigned short f2bf_rne(float f) {
    unsigned int u = __float_as_uint(f);
    unsigned int r = (u + 0x7FFFu + ((u >> 16) & 1u)) >> 16;
    return (unsigned short)r;
}
static __device__ __forceinline__ float bf2f(unsigned short h) {
    return __uint_as_float(((unsigned int)h) << 16);
}

// ---------- combined prep: pairs | cwt (LDS transpose) | manipw | lint4 ----------
__global__ void k_prep(const float* __restrict__ emb_e, const float* __restrict__ emb_f,
                       const float* __restrict__ cw_e, const float* __restrict__ cw_f,
                       const float* __restrict__ mcw, const float* __restrict__ mlw,
                       float* __restrict__ P, float* __restrict__ cwT,
                       float* __restrict__ Wc, float* __restrict__ Lint4) {
    __shared__ float T[48][66];   // cwt transpose tile: rows kh*16+il, cols o_local
    int bid = blockIdx.x;
    int t = threadIdx.x;
    if (bid < PB_PAIRS) {                  // pairs: P[br][q][c]
        int q = bid % NP, br = bid / NP;
        const float* emb = br ? emb_f : emb_e;
        int t1 = q / NV, t2 = q % NV;
        float* outp = P + ((size_t)br * NP + q) * EMBD;
        for (int c = t; c < EMBD; c += 256)
            outp[c] = fmaxf(emb[t1 * EMBD + c], emb[t2 * EMBD + c]);
    } else if (bid < PB_PAIRS + PB_CWT) {  // cwt: coalesced read + LDS transpose
        int cb = bid - PB_PAIRS;           // 0..255
        int ic = cb & 31;                  // i-chunk (16 i's)
        int oc = (cb >> 5) & 3;            // o-chunk (64 o's)
        int br = cb >> 7;                  // branch
        int i0 = ic * 16, o0 = oc * 64;
        const float* cw = br ? cw_f : cw_e;
        int ol = t >> 2, part = t & 3;     // o_local 0..63, i-quarter 0..3
        // thread reads the kw=1 column for its 4 i's (contiguous span per (o,part))
        const float* src = cw + ((size_t)(o0 + ol) * EMBD + i0) * 9 + part * 36;
        #pragma unroll
        for (int kk = 0; kk < 12; ++kk) {
            int ii = kk >> 2;              // wrong order? no: iterate i (4) x kh (3)
            int kh = kk & 3;
            if (kh == 3) continue;         // unreachable layout guard
            // use explicit decomposition below instead
        }
        #pragma unroll
        for (int ii = 0; ii < 4; ++ii)
            #pragma unroll
            for (int kh = 0; kh < 3; ++kh)
                T[kh * 16 + part * 4 + ii][ol] = src[ii * 9 + kh * 3 + 1];
        __syncthreads();
        int lane = t & 63, r0 = t >> 6;
        for (int rr = r0; rr < 48; rr += 4) {
            int kh = rr >> 4, il = rr & 15;
            cwT[(((size_t)(br * 3 + kh)) * EMBD + i0 + il) * OC + o0 + lane] = T[rr][lane];
        }
    } else if (bid < PB_PAIRS + PB_CWT + PB_MANIPW) {  // manipw (small, gather ok)
        int idx = (bid - PB_PAIRS - PB_CWT) * 256 + t;
        int o = idx & 63;
        int i = (idx >> 6) & 127;
        int cls = idx >> 13;
        const float* base = mcw + ((size_t)(o * 128 + i) * 3) * 3 + 1;
        float v = 0.f;
        if (cls != 2) { v += base[3]; v += base[6]; }
        else          { v += base[0]; v += base[3]; }
        if (cls == 1)   v += base[0];
        Wc[idx] = v;
    } else {                                // lint split-4 over h
        int lb = bid - (PB_PAIRS + PB_CWT + PB_MANIPW);   // 0..255
        int o = lb >> 2, hq = lb & 3;
        int h0 = hq * 32;
        int hs = h0 < 1 ? 1 : h0;
        int he = (h0 + 32) > 127 ? 127 : (h0 + 32);
        float s = 0.f;
        for (int h = hs; h < he; h++)
            s += mlw[((size_t)(o * H2 + h)) * MJ + t];
        Lint4[(size_t)hq * LINT4 + o * 256 + t] = s;
    }
}

// ---------- pair contributions, split-K x4: Cpart[ks][(br*NP+q)*3+kh][o] ----------
__global__ __launch_bounds__(256) void k_contrib(
        const float* __restrict__ P, const float* __restrict__ cwT,
        float* __restrict__ Cpart) {
    int bid = blockIdx.x;               // ((br*3+kh)*28+qg)*4+ks
    int ks = bid & 3;
    int qg = (bid >> 2) % 28;
    int kh = ((bid >> 2) / 28) % 3;
    int br = bid / (4 * 28 * 3);
    int o = threadIdx.x;

    __shared__ float Pl[7][128];
    for (int idx = o; idx < 7 * 128; idx += 256) {
        int row = idx >> 7, col = idx & 127;
        Pl[row][col] = P[((size_t)br * NP + qg * 7 + row) * EMBD + ks * 128 + col];
    }
    __syncthreads();

    const float* w = cwT + ((size_t)(br * 3 + kh) * EMBD + ks * 128) * OC + o;
    float acc[7];
    #pragma unroll
    for (int qq = 0; qq < 7; qq++) acc[qq] = 0.f;
    #pragma unroll 8
    for (int i = 0; i < 128; i++) {
        float wv = w[(size_t)i * OC];
        #pragma unroll
        for (int qq = 0; qq < 7; qq++) acc[qq] = fmaf(wv, Pl[qq][i], acc[qq]);
    }
    float* dst = Cpart + (size_t)ks * CSTRIDE + (((size_t)br * NP + qg * 7) * 3 + kh) * OC + o;
    #pragma unroll
    for (int qq = 0; qq < 7; qq++)
        dst[(size_t)qq * 3 * OC] = acc[qq];
}

// ---------- reduce Cpart (+ fold cb) and Lint4 ----------
__global__ __launch_bounds__(256) void k_cred(
        const float* __restrict__ Cpart, const float* __restrict__ cb_e,
        const float* __restrict__ cb_f, const float* __restrict__ Lint4,
        float* __restrict__ C, float* __restrict__ Lint) {
    int bid = blockIdx.x;
    int t = threadIdx.x;
    if (bid < CROWS) {                      // 1176 blocks: C reduce
        int idx = bid * 256 + t;
        float s = Cpart[idx] + Cpart[CSTRIDE + idx]
                + Cpart[2 * CSTRIDE + idx] + Cpart[3 * CSTRIDE + idx];
        int o = idx & 255;
        int kh = (idx >> 8) % 3;
        if (kh == 1) {
            int br = idx >= (NP * 3 * 256);
            s += br ? cb_f[o] : cb_e[o];
        }
        C[idx] = s;
    } else {                                 // 64 blocks: Lint reduce
        int idx = (bid - CROWS) * 256 + t;
        Lint[idx] = Lint4[idx] + Lint4[LINT4 + idx]
                  + Lint4[2 * LINT4 + idx] + Lint4[3 * LINT4 + idx];
    }
}

// ---------- MFMA GEMM: partial[h][b][j] = sum_o Y[b,h,o]*lw[(o*H2+h)*JD+j] ----------
template <int X3>
__global__ __launch_bounds__(512) void k_gemm(
        const int* __restrict__ tok, const float* __restrict__ C,
        const float* __restrict__ lw, float* __restrict__ partial) {
    __shared__ unsigned short Ah[2][128][36];
    __shared__ unsigned short Al[2][128][36];
    __shared__ unsigned short Bh[2][128][36];
    __shared__ unsigned short Bl[2][128][36];

    const int h  = blockIdx.x;
    const int B0 = blockIdx.y * 128;
    const int t  = threadIdx.x;

    // ---- A gather setup (thread: row am, k-quad kq)
    const int am = t >> 2;
    const int kq = (t & 3) * 8;
    const int* tb = tok + (size_t)(B0 + am) * LL;
    const int q1 = tb[2 * h] * NV + tb[2 * h + 1];
    const float* r1 = C + ((size_t)q1 * 3 + 1) * OC + kq;
    const float* r0 = nullptr;
    const float* r2 = nullptr;
    if (h > 0)      { int q0 = tb[2 * h - 2] * NV + tb[2 * h - 1]; r0 = C + ((size_t)q0 * 3 + 0) * OC + kq; }
    if (h < H2 - 1) { int q2 = tb[2 * h + 2] * NV + tb[2 * h + 3]; r2 = C + ((size_t)q2 * 3 + 2) * OC + kq; }

    // ---- B setup (thread: k-row ko, 8 j's at j0)
    const int ko = t & 31;
    const int j0 = (t >> 5) * 8;
    const float* wsrc = lw + ((size_t)ko * H2 + h) * JD + j0;

    float4 ya0, ya1, yb0, yb1, yc0, yc1, wv0, wv1;

    auto load = [&](int s) {
        const float* p1 = r1 + s * 32;
        ya0 = *(const float4*)(p1);
        ya1 = *(const float4*)(p1 + 4);
        if (r0) { const float* p0 = r0 + s * 32; yb0 = *(const float4*)(p0); yb1 = *(const float4*)(p0 + 4); }
        else    { yb0 = make_float4(0, 0, 0, 0); yb1 = yb0; }
        if (r2) { const float* p2 = r2 + s * 32; yc0 = *(const float4*)(p2); yc1 = *(const float4*)(p2 + 4); }
        else    { yc0 = make_float4(0, 0, 0, 0); yc1 = yc0; }
        const float* pw = wsrc + (size_t)s * 32 * H2 * JD;
        wv0 = *(const float4*)(pw);
        wv1 = *(const float4*)(pw + 4);
    };

    auto store = [&](int buf) {
        float y[8];
        y[0] = ya0.x + yb0.x + yc0.x; y[1] = ya0.y + yb0.y + yc0.y;
        y[2] = ya0.z + yb0.z + yc0.z; y[3] = ya0.w + yb0.w + yc0.w;
        y[4] = ya1.x + yb1.x + yc1.x; y[5] = ya1.y + yb1.y + yc1.y;
        y[6] = ya1.z + yb1.z + yc1.z; y[7] = ya1.w + yb1.w + yc1.w;
        unsigned short hi[8];
        #pragma unroll
        for (int e = 0; e < 8; ++e) hi[e] = f2bf_rne(y[e]);
        uint2 u0, u1;
        u0.x = (unsigned)hi[0] | ((unsigned)hi[1] << 16);
        u0.y = (unsigned)hi[2] | ((unsigned)hi[3] << 16);
        u1.x = (unsigned)hi[4] | ((unsigned)hi[5] << 16);
        u1.y = (unsigned)hi[6] | ((unsigned)hi[7] << 16);
        *(uint2*)&Ah[buf][am][kq]     = u0;
        *(uint2*)&Ah[buf][am][kq + 4] = u1;
        if (X3) {
            unsigned short lo[8];
            #pragma unroll
            for (int e = 0; e < 8; ++e) lo[e] = f2bf_rne(y[e] - bf2f(hi[e]));
            uint2 v0, v1;
            v0.x = (unsigned)lo[0] | ((unsigned)lo[1] << 16);
            v0.y = (unsigned)lo[2] | ((unsigned)lo[3] << 16);
            v1.x = (unsigned)lo[4] | ((unsigned)lo[5] << 16);
            v1.y = (unsigned)lo[6] | ((unsigned)lo[7] << 16);
            *(uint2*)&Al[buf][am][kq]     = v0;
            *(uint2*)&Al[buf][am][kq + 4] = v1;
        }
        float wv[8] = {wv0.x, wv0.y, wv0.z, wv0.w, wv1.x, wv1.y, wv1.z, wv1.w};
        #pragma unroll
        for (int e = 0; e < 8; ++e) {
            unsigned short wh = f2bf_rne(wv[e]);
            Bh[buf][j0 + e][ko] = wh;
            if (X3) Bl[buf][j0 + e][ko] = f2bf_rne(wv[e] - bf2f(wh));
        }
    };

    // ---- compute mapping
    const int lane = t & 63, wid = t >> 6;
    const int Wm = (wid >> 2) * 64;     // 0 or 64
    const int Wn = (wid & 3) * 32;      // 0,32,64,96
    const int fr = lane & 15;
    const int g8 = (lane >> 4) * 8;

    f32x4 acc[4][2] = {};

    auto rd8 = [&](const unsigned short* p) -> s16x8 {
        union { s16x8 v; uint2 u[2]; } tmp;
        tmp.u[0] = *(const uint2*)(p);
        tmp.u[1] = *(const uint2*)(p + 4);
        return tmp.v;
    };

    auto compute = [&](int buf) {
        s16x8 a_h[4], b_h[2];
        #pragma unroll
        for (int mf = 0; mf < 4; ++mf) a_h[mf] = rd8(&Ah[buf][Wm + mf * 16 + fr][g8]);
        #pragma unroll
        for (int nf = 0; nf < 2; ++nf) b_h[nf] = rd8(&Bh[buf][Wn + nf * 16 + fr][g8]);
        #pragma unroll
        for (int mf = 0; mf < 4; ++mf)
            #pragma unroll
            for (int nf = 0; nf < 2; ++nf)
                acc[mf][nf] = __builtin_amdgcn_mfma_f32_16x16x32_bf16(a_h[mf], b_h[nf], acc[mf][nf], 0, 0, 0);
        if (X3) {
            s16x8 a_l[4], b_l[2];
            #pragma unroll
            for (int mf = 0; mf < 4; ++mf) a_l[mf] = rd8(&Al[buf][Wm + mf * 16 + fr][g8]);
            #pragma unroll
            for (int nf = 0; nf < 2; ++nf) b_l[nf] = rd8(&Bl[buf][Wn + nf * 16 + fr][g8]);
            #pragma unroll
            for (int mf = 0; mf < 4; ++mf)
                #pragma unroll
                for (int nf = 0; nf < 2; ++nf) {
                    acc[mf][nf] = __builtin_amdgcn_mfma_f32_16x16x32_bf16(a_h[mf], b_l[nf], acc[mf][nf], 0, 0, 0);
                    acc[mf][nf] = __builtin_amdgcn_mfma_f32_16x16x32_bf16(a_l[mf], b_h[nf], acc[mf][nf], 0, 0, 0);
                }
        }
    };

    // ---- main loop
    load(0);
    store(0);
    __syncthreads();
    for (int s = 0; s < 8; ++s) {
        if (s < 7) load(s + 1);
        compute(s & 1);
        if (s < 7) store((s + 1) & 1);
        __syncthreads();
    }

    // ---- epilogue: D mapping col=lane&15, row=4*(lane>>4)+reg
    float* pb = partial + ((size_t)h * BB + B0 + Wm) * JD + Wn;
    #pragma unroll
    for (int mf = 0; mf < 4; ++mf)
        #pragma unroll
        for (int nf = 0; nf < 2; ++nf)
            #pragma unroll
            for (int r = 0; r < 4; ++r) {
                int row = mf * 16 + (lane >> 4) * 4 + r;
                int col = nf * 16 + fr;
                pb[(size_t)row * JD + col] = acc[mf][nf][r];
            }
}

// ---------- fuse E: reduce + softmax + manip conv + manip linear + tokens ----------
__global__ __launch_bounds__(256) void k_fuseE(
        const float* __restrict__ partial, const float* __restrict__ elb,
        const float* __restrict__ Wc, const float* __restrict__ mcb,
        const float* __restrict__ mlw, const float* __restrict__ Lint,
        const float* __restrict__ mlb, int* __restrict__ tokens) {
    int b = blockIdx.x, t = threadIdx.x;
    __shared__ float S[2][128];
    __shared__ float eo[128];
    __shared__ float m3[3][64];
    __shared__ float red[128];

    int j = t & 127, hh = t >> 7;
    float s = 0.f;
    for (int h = hh * 64; h < hh * 64 + 64; ++h)
        s += partial[((size_t)h * BB + b) * JD + j];
    S[hh][j] = s;
    __syncthreads();
    if (t < 128) {
        float v = S[0][t] + S[1][t] + elb[t];
        S[0][t] = v;
        red[t] = v;
    }
    __syncthreads();
    for (int st = 64; st > 0; st >>= 1) {
        if (t < st) red[t] = fmaxf(red[t], red[t + st]);
        __syncthreads();
    }
    float mx = red[0];
    __syncthreads();
    if (t < 128) {
        float e = expf(S[0][t] - mx);
        eo[t] = e;
        red[t] = e;
    }
    __syncthreads();
    for (int st = 64; st > 0; st >>= 1) {
        if (t < st) red[t] += red[t + st];
        __syncthreads();
    }
    float inv = 1.f / red[0];
    __syncthreads();
    if (t < 128) eo[t] *= inv;
    __syncthreads();
    // manip conv values
    if (t < 192) {
        int cls = t >> 6, o = t & 63;
        float a = mcb[o];
        const float* wp = Wc + (size_t)cls * 128 * 64 + o;
        for (int i = 0; i < 128; ++i) a = fmaf(eo[i], wp[(size_t)i * 64], a);
        m3[cls][o] = fmaxf(a, 0.f);
    }
    __syncthreads();
    // manip linear + token quantization (t = j 0..255)
    float a = mlb[t];
    for (int o = 0; o < MO; ++o) {
        a = fmaf(m3[0][o], mlw[((size_t)(o * H2 + 0)) * MJ + t], a);
        a = fmaf(m3[1][o], Lint[(size_t)o * MJ + t], a);
        a = fmaf(m3[2][o], mlw[((size_t)(o * H2 + 127)) * MJ + t], a);
    }
    tokens[(size_t)b * LL + t] = ((int)floorf(fabsf(a) * 100.f)) % NV;
}

// ---------- fuse F: reduce + head linear + softmax(14) ----------
__global__ __launch_bounds__(256) void k_fuseF(
        const float* __restrict__ partial, const float* __restrict__ flb1,
        const float* __restrict__ fl2, const float* __restrict__ fb2,
        float* __restrict__ outp) {
    int b = blockIdx.x, t = threadIdx.x;
    __shared__ float S[2][128];
    __shared__ float f1[128];
    __shared__ float sl[NV];
    int j = t & 127, hh = t >> 7;
    float s = 0.f;
    for (int h = hh * 64; h < hh * 64 + 64; ++h)
        s += partial[((size_t)h * BB + b) * JD + j];
    S[hh][j] = s;
    __syncthreads();
    if (t < 128) f1[t] = S[0][t] + S[1][t] + flb1[t];
    __syncthreads();
    if (t < NV) {
        float a = fb2[t];
        for (int jj = 0; jj < 128; ++jj) a = fmaf(f1[jj], fl2[(size_t)jj * NV + t], a);
        sl[t] = a;
    }
    __syncthreads();
    if (t < NV) {
        float mx = -1e30f;
        for (int u = 0; u < NV; ++u) mx = fmaxf(mx, sl[u]);
        float ss = 0.f;
        for (int u = 0; u < NV; ++u) ss += expf(sl[u] - mx);
        outp[(size_t)b * NV + t] = expf(sl[t] - mx) / ss;
    }
}

extern "C" void kernel_launch(void* const* d_in, const int* in_sizes, int n_in,
                              void* d_out, int out_size, void* d_ws, size_t ws_size,
                              hipStream_t stream) {
    const int*   x    = (const int*)d_in[0];
    const float* eemb = (const float*)d_in[1];
    const float* ecw  = (const float*)d_in[2];
    const float* ecb  = (const float*)d_in[3];
    const float* elw  = (const float*)d_in[4];
    const float* elb  = (const float*)d_in[5];
    // d_in[6] rand_proj: provably unused (fog_of_war returns identity permutation)
    const float* mcw  = (const float*)d_in[7];
    const float* mcb  = (const float*)d_in[8];
    const float* mlw  = (const float*)d_in[9];
    const float* mlb  = (const float*)d_in[10];
    const float* femb = (const float*)d_in[11];
    const float* fcw  = (const float*)d_in[12];
    const float* fcb  = (const float*)d_in[13];
    const float* flw1 = (const float*)d_in[14];
    const float* flb1 = (const float*)d_in[15];
    const float* fl2  = (const float*)d_in[16];
    const float* fb2  = (const float*)d_in[17];
    float* outp = (float*)d_out;

    char* w = (char*)d_ws;
    size_t off = 0;
    auto alloc = [&](size_t bytes) {
        void* p = w + off;
        off = (off + bytes + 255) & ~(size_t)255;
        return p;
    };
    float* P      = (float*)alloc(2ull * NP * EMBD * 4);        // 0.8 MB
    float* cwT    = (float*)alloc(2ull * 3 * EMBD * OC * 4);    // 3.1 MB
    float* C      = (float*)alloc((size_t)CSTRIDE * 4);         // 1.2 MB
    float* Cpart  = (float*)alloc(4ull * CSTRIDE * 4);          // 4.8 MB
    float* Wc     = (float*)alloc(3ull * 128 * 64 * 4);
    float* Lint   = (float*)alloc(64ull * MJ * 4);
    float* Lint4  = (float*)alloc(4ull * LINT4 * 4);            // 0.25 MB
    int*   tokens = (int*)alloc((size_t)BB * LL * 4);
    float* partial= (float*)alloc((size_t)H2 * BB * JD * 4);    // 16.8 MB

    const float* C_e = C;
    const float* C_f = C + (size_t)NP * 3 * OC;

    // ---- prep (pairs | cwt | manipw | lint4) ----
    k_prep<<<PB_PAIRS + PB_CWT + PB_MANIPW + PB_LINT, 256, 0, stream>>>(
        eemb, femb, ecw, fcw, mcw, mlw, P, cwT, Wc, Lint4);
    // ---- pair contributions (split-K x4) + reduce ----
    k_contrib<<<2 * 3 * 28 * 4, 256, 0, stream>>>(P, cwT, Cpart);
    k_cred<<<CROWS + 64, 256, 0, stream>>>(Cpart, ecb, fcb, Lint4, C, Lint);

    // ---- enemy branch (bf16x3 MFMA — token path needs near-fp32) ----
    k_gemm<1><<<dim3(H2, 2), 512, 0, stream>>>(x, C_e, elw, partial);
    k_fuseE<<<BB, 256, 0, stream>>>(partial, elb, Wc, mcb, mlw, Lint, mlb, tokens);

    // ---- friend branch (plain bf16 MFMA) ----
    k_gemm<0><<<dim3(H2, 2), 512, 0, stream>>>(tokens, C_f, flw1, partial);
    k_fuseF<<<BB, 256, 0, stream>>>(partial, flb1, fl2, fb2, outp);
}

// Round 7
// 94.633 us; speedup vs baseline: 4.9959x; 1.0565x over previous
//
#include <hip/hip_runtime.h>
#include <hip/hip_bf16.h>
#include <math.h>

#define BB    256   // batch
#define LL    256   // seq len
#define NV    14    // vocab
#define EMBD  512
#define H2    128   // L//2
#define OC    256   // branch conv out channels
#define NP    196   // 14*14 ordered token pairs
#define JD    128   // branch linear out
#define MO    64    // manip conv out channels
#define MJ    256   // manip linear out

// prep block ranges
#define PB_PAIRS  392
#define PB_CWT    256                   // 2 br * 4 o-chunks * 32 i-chunks
#define PB_MANIPW 96
#define PB_LINT   64

using s16x8 = __attribute__((ext_vector_type(8))) short;
using f32x4 = __attribute__((ext_vector_type(4))) float;

static __device__ __forceinline__ unsigned short f2bf_rne(float f) {
    unsigned int u = __float_as_uint(f);
    unsigned int r = (u + 0x7FFFu + ((u >> 16) & 1u)) >> 16;
    return (unsigned short)r;
}
static __device__ __forceinline__ float bf2f(unsigned short h) {
    return __uint_as_float(((unsigned int)h) << 16);
}

// ---------- combined prep: pairs | cwt (LDS transpose) | manipw | lint ----------
__global__ void k_prep(const float* __restrict__ emb_e, const float* __restrict__ emb_f,
                       const float* __restrict__ cw_e, const float* __restrict__ cw_f,
                       const float* __restrict__ mcw, const float* __restrict__ mlw,
                       float* __restrict__ P, float* __restrict__ cwT,
                       float* __restrict__ Wc, float* __restrict__ Lint) {
    __shared__ float T[48][66];   // cwt transpose tile
    int bid = blockIdx.x;
    int t = threadIdx.x;
    if (bid < PB_PAIRS) {                  // pairs: P[br][q][c]
        int q = bid % NP, br = bid / NP;
        const float* emb = br ? emb_f : emb_e;
        int t1 = q / NV, t2 = q % NV;
        float* outp = P + ((size_t)br * NP + q) * EMBD;
        for (int c = t; c < EMBD; c += 256)
            outp[c] = fmaxf(emb[t1 * EMBD + c], emb[t2 * EMBD + c]);
    } else if (bid < PB_PAIRS + PB_CWT) {  // cwt: coalesced read + LDS transpose
        int cb = bid - PB_PAIRS;           // 0..255
        int ic = cb & 31;                  // i-chunk (16 i's)
        int oc = (cb >> 5) & 3;            // o-chunk (64 o's)
        int br = cb >> 7;                  // branch
        int i0 = ic * 16, o0 = oc * 64;
        const float* cw = br ? cw_f : cw_e;
        int ol = t >> 2, part = t & 3;     // o_local 0..63, i-quarter 0..3
        const float* src = cw + ((size_t)(o0 + ol) * EMBD + i0) * 9 + part * 36;
        #pragma unroll
        for (int ii = 0; ii < 4; ++ii)
            #pragma unroll
            for (int kh = 0; kh < 3; ++kh)
                T[kh * 16 + part * 4 + ii][ol] = src[ii * 9 + kh * 3 + 1];
        __syncthreads();
        int lane = t & 63, r0 = t >> 6;
        for (int rr = r0; rr < 48; rr += 4) {
            int kh = rr >> 4, il = rr & 15;
            cwT[(((size_t)(br * 3 + kh)) * EMBD + i0 + il) * OC + o0 + lane] = T[rr][lane];
        }
    } else if (bid < PB_PAIRS + PB_CWT + PB_MANIPW) {  // manipw
        int idx = (bid - PB_PAIRS - PB_CWT) * 256 + t;
        int o = idx & 63;
        int i = (idx >> 6) & 127;
        int cls = idx >> 13;
        const float* base = mcw + ((size_t)(o * 128 + i) * 3) * 3 + 1;
        float v = 0.f;
        if (cls != 2) { v += base[3]; v += base[6]; }
        else          { v += base[0]; v += base[3]; }
        if (cls == 1)   v += base[0];
        Wc[idx] = v;
    } else {                                // lint (full interior sum)
        int o = bid - (PB_PAIRS + PB_CWT + PB_MANIPW);   // 0..63
        float s = 0.f;
        for (int h = 1; h <= 126; h++)
            s += mlw[((size_t)(o * H2 + h)) * MJ + t];
        Lint[o * 256 + t] = s;
    }
}

// ---------- pair contributions, full K, q-batch 4: C[(br*NP+q)*3+kh][o] ----------
__global__ __launch_bounds__(256) void k_contrib(
        const float* __restrict__ P, const float* __restrict__ cwT,
        const float* __restrict__ cb_e, const float* __restrict__ cb_f,
        float* __restrict__ C) {
    int bid = blockIdx.x;               // (br*3+kh)*49+qg
    int qg = bid % 49;
    int kh = (bid / 49) % 3;
    int br = bid / 147;
    int o = threadIdx.x;

    __shared__ float Pl[4][512];
    for (int idx = o; idx < 4 * 512; idx += 256) {
        int row = idx >> 9, col = idx & 511;
        Pl[row][col] = P[((size_t)br * NP + qg * 4 + row) * EMBD + col];
    }
    __syncthreads();

    const float* w = cwT + ((size_t)(br * 3 + kh) * EMBD) * OC + o;
    float acc[4] = {0.f, 0.f, 0.f, 0.f};
    #pragma unroll 8
    for (int i = 0; i < 512; i++) {
        float wv = w[(size_t)i * OC];
        #pragma unroll
        for (int qq = 0; qq < 4; qq++) acc[qq] = fmaf(wv, Pl[qq][i], acc[qq]);
    }
    float cbv = (kh == 1) ? (br ? cb_f[o] : cb_e[o]) : 0.f;
    #pragma unroll
    for (int qq = 0; qq < 4; qq++)
        C[(((size_t)br * NP + qg * 4 + qq) * 3 + kh) * OC + o] = acc[qq] + cbv;
}

// ---------- MFMA GEMM: partial[b][hB][j] = sum_o Y[b,h,o]*lw[(o*H2+h)*JD+j] ----------
// M-tile 64, grid (H2, 4) = 512 blocks, 2 blocks/CU (54KB LDS), 8 waves 2m x 4n.
template <int X3>
__global__ __launch_bounds__(512) void k_gemm(
        const int* __restrict__ tok, const float* __restrict__ C,
        const float* __restrict__ lw, float* __restrict__ partial) {
    __shared__ unsigned short Ah[2][64][36];
    __shared__ unsigned short Al[2][64][36];
    __shared__ unsigned short Bh[2][128][36];
    __shared__ unsigned short Bl[2][128][36];

    const int h  = blockIdx.x;
    const int B0 = blockIdx.y * 64;
    const int t  = threadIdx.x;

    // ---- A gather setup (thread: row am 0..63, k-quad kq of 4 floats)
    const int am = t >> 3;
    const int kq = (t & 7) * 4;
    const int* tb = tok + (size_t)(B0 + am) * LL;
    const int q1 = tb[2 * h] * NV + tb[2 * h + 1];
    const float* r1 = C + ((size_t)q1 * 3 + 1) * OC + kq;
    const float* r0 = nullptr;
    const float* r2 = nullptr;
    if (h > 0)      { int q0 = tb[2 * h - 2] * NV + tb[2 * h - 1]; r0 = C + ((size_t)q0 * 3 + 0) * OC + kq; }
    if (h < H2 - 1) { int q2 = tb[2 * h + 2] * NV + tb[2 * h + 3]; r2 = C + ((size_t)q2 * 3 + 2) * OC + kq; }

    // ---- B setup (thread: k-row ko 0..31, 8 j's at j0)
    const int ko = t & 31;
    const int j0 = (t >> 5) * 8;
    const float* wsrc = lw + ((size_t)ko * H2 + h) * JD + j0;

    float4 ya, yb, yc, wv0, wv1;

    auto load = [&](int s) {
        ya = *(const float4*)(r1 + s * 32);
        if (r0) yb = *(const float4*)(r0 + s * 32);
        else    yb = make_float4(0, 0, 0, 0);
        if (r2) yc = *(const float4*)(r2 + s * 32);
        else    yc = make_float4(0, 0, 0, 0);
        const float* pw = wsrc + (size_t)s * 32 * H2 * JD;
        wv0 = *(const float4*)(pw);
        wv1 = *(const float4*)(pw + 4);
    };

    auto store = [&](int buf) {
        float y[4];
        y[0] = ya.x + yb.x + yc.x; y[1] = ya.y + yb.y + yc.y;
        y[2] = ya.z + yb.z + yc.z; y[3] = ya.w + yb.w + yc.w;
        unsigned short hi[4];
        #pragma unroll
        for (int e = 0; e < 4; ++e) hi[e] = f2bf_rne(y[e]);
        uint2 u;
        u.x = (unsigned)hi[0] | ((unsigned)hi[1] << 16);
        u.y = (unsigned)hi[2] | ((unsigned)hi[3] << 16);
        *(uint2*)&Ah[buf][am][kq] = u;
        if (X3) {
            uint2 v;
            unsigned short lo[4];
            #pragma unroll
            for (int e = 0; e < 4; ++e) lo[e] = f2bf_rne(y[e] - bf2f(hi[e]));
            v.x = (unsigned)lo[0] | ((unsigned)lo[1] << 16);
            v.y = (unsigned)lo[2] | ((unsigned)lo[3] << 16);
            *(uint2*)&Al[buf][am][kq] = v;
        }
        float wv[8] = {wv0.x, wv0.y, wv0.z, wv0.w, wv1.x, wv1.y, wv1.z, wv1.w};
        #pragma unroll
        for (int e = 0; e < 8; ++e) {
            unsigned short wh = f2bf_rne(wv[e]);
            Bh[buf][j0 + e][ko] = wh;
            if (X3) Bl[buf][j0 + e][ko] = f2bf_rne(wv[e] - bf2f(wh));
        }
    };

    // ---- compute mapping: 8 waves = 2m x 4n; wave tile 32m x 32n
    const int lane = t & 63, wid = t >> 6;
    const int Wm = (wid >> 2) * 32;     // 0 or 32
    const int Wn = (wid & 3) * 32;      // 0,32,64,96
    const int fr = lane & 15;
    const int g8 = (lane >> 4) * 8;

    f32x4 acc[2][2] = {};

    auto rd8 = [&](const unsigned short* p) -> s16x8 {
        union { s16x8 v; uint2 u[2]; } tmp;
        tmp.u[0] = *(const uint2*)(p);
        tmp.u[1] = *(const uint2*)(p + 4);
        return tmp.v;
    };

    auto compute = [&](int buf) {
        s16x8 a_h[2], b_h[2];
        #pragma unroll
        for (int mf = 0; mf < 2; ++mf) a_h[mf] = rd8(&Ah[buf][Wm + mf * 16 + fr][g8]);
        #pragma unroll
        for (int nf = 0; nf < 2; ++nf) b_h[nf] = rd8(&Bh[buf][Wn + nf * 16 + fr][g8]);
        #pragma unroll
        for (int mf = 0; mf < 2; ++mf)
            #pragma unroll
            for (int nf = 0; nf < 2; ++nf)
                acc[mf][nf] = __builtin_amdgcn_mfma_f32_16x16x32_bf16(a_h[mf], b_h[nf], acc[mf][nf], 0, 0, 0);
        if (X3) {
            s16x8 a_l[2], b_l[2];
            #pragma unroll
            for (int mf = 0; mf < 2; ++mf) a_l[mf] = rd8(&Al[buf][Wm + mf * 16 + fr][g8]);
            #pragma unroll
            for (int nf = 0; nf < 2; ++nf) b_l[nf] = rd8(&Bl[buf][Wn + nf * 16 + fr][g8]);
            #pragma unroll
            for (int mf = 0; mf < 2; ++mf)
                #pragma unroll
                for (int nf = 0; nf < 2; ++nf) {
                    acc[mf][nf] = __builtin_amdgcn_mfma_f32_16x16x32_bf16(a_h[mf], b_l[nf], acc[mf][nf], 0, 0, 0);
                    acc[mf][nf] = __builtin_amdgcn_mfma_f32_16x16x32_bf16(a_l[mf], b_h[nf], acc[mf][nf], 0, 0, 0);
                }
        }
    };

    // ---- main loop
    load(0);
    store(0);
    __syncthreads();
    for (int s = 0; s < 8; ++s) {
        if (s < 7) load(s + 1);
        compute(s & 1);
        if (s < 7) store((s + 1) & 1);
        __syncthreads();
    }

    // ---- epilogue: partial[b][h][j]; D mapping col=lane&15, row=4*(lane>>4)+reg
    float* pb = partial + (((size_t)(B0 + Wm)) * H2 + h) * JD + Wn;
    #pragma unroll
    for (int mf = 0; mf < 2; ++mf)
        #pragma unroll
        for (int nf = 0; nf < 2; ++nf)
            #pragma unroll
            for (int r = 0; r < 4; ++r) {
                int row = mf * 16 + (lane >> 4) * 4 + r;
                int col = nf * 16 + fr;
                pb[(size_t)row * H2 * JD + col] = acc[mf][nf][r];
            }
}

// ---------- fuse E: reduce + softmax + manip conv + manip linear + tokens ----------
__global__ __launch_bounds__(256) void k_fuseE(
        const float* __restrict__ partial, const float* __restrict__ elb,
        const float* __restrict__ Wc, const float* __restrict__ mcb,
        const float* __restrict__ mlw, const float* __restrict__ Lint,
        const float* __restrict__ mlb, int* __restrict__ tokens) {
    int b = blockIdx.x, t = threadIdx.x;
    __shared__ float S[2][128];
    __shared__ float eo[128];
    __shared__ float m3[3][64];
    __shared__ float red[128];

    int j = t & 127, hh = t >> 7;
    float s = 0.f;
    const float* pbase = partial + (size_t)b * H2 * JD + j;
    for (int h = hh * 64; h < hh * 64 + 64; ++h)
        s += pbase[(size_t)h * JD];
    S[hh][j] = s;
    __syncthreads();
    if (t < 128) {
        float v = S[0][t] + S[1][t] + elb[t];
        S[0][t] = v;
        red[t] = v;
    }
    __syncthreads();
    for (int st = 64; st > 0; st >>= 1) {
        if (t < st) red[t] = fmaxf(red[t], red[t + st]);
        __syncthreads();
    }
    float mx = red[0];
    __syncthreads();
    if (t < 128) {
        float e = expf(S[0][t] - mx);
        eo[t] = e;
        red[t] = e;
    }
    __syncthreads();
    for (int st = 64; st > 0; st >>= 1) {
        if (t < st) red[t] += red[t + st];
        __syncthreads();
    }
    float inv = 1.f / red[0];
    __syncthreads();
    if (t < 128) eo[t] *= inv;
    __syncthreads();
    // manip conv values
    if (t < 192) {
        int cls = t >> 6, o = t & 63;
        float a = mcb[o];
        const float* wp = Wc + (size_t)cls * 128 * 64 + o;
        for (int i = 0; i < 128; ++i) a = fmaf(eo[i], wp[(size_t)i * 64], a);
        m3[cls][o] = fmaxf(a, 0.f);
    }
    __syncthreads();
    // manip linear + token quantization (t = j 0..255)
    float a = mlb[t];
    for (int o = 0; o < MO; ++o) {
        a = fmaf(m3[0][o], mlw[((size_t)(o * H2 + 0)) * MJ + t], a);
        a = fmaf(m3[1][o], Lint[(size_t)o * MJ + t], a);
        a = fmaf(m3[2][o], mlw[((size_t)(o * H2 + 127)) * MJ + t], a);
    }
    tokens[(size_t)b * LL + t] = ((int)floorf(fabsf(a) * 100.f)) % NV;
}

// ---------- fuse F: reduce + head linear + softmax(14) ----------
__global__ __launch_bounds__(256) void k_fuseF(
        const float* __restrict__ partial, const float* __restrict__ flb1,
        const float* __restrict__ fl2, const float* __restrict__ fb2,
        float* __restrict__ outp) {
    int b = blockIdx.x, t = threadIdx.x;
    __shared__ float S[2][128];
    __shared__ float f1[128];
    __shared__ float sl[NV];
    int j = t & 127, hh = t >> 7;
    float s = 0.f;
    const float* pbase = partial + (size_t)b * H2 * JD + j;
    for (int h = hh * 64; h < hh * 64 + 64; ++h)
        s += pbase[(size_t)h * JD];
    S[hh][j] = s;
    __syncthreads();
    if (t < 128) f1[t] = S[0][t] + S[1][t] + flb1[t];
    __syncthreads();
    if (t < NV) {
        float a = fb2[t];
        for (int jj = 0; jj < 128; ++jj) a = fmaf(f1[jj], fl2[(size_t)jj * NV + t], a);
        sl[t] = a;
    }
    __syncthreads();
    if (t < NV) {
        float mx = -1e30f;
        for (int u = 0; u < NV; ++u) mx = fmaxf(mx, sl[u]);
        float ss = 0.f;
        for (int u = 0; u < NV; ++u) ss += expf(sl[u] - mx);
        outp[(size_t)b * NV + t] = expf(sl[t] - mx) / ss;
    }
}

extern "C" void kernel_launch(void* const* d_in, const int* in_sizes, int n_in,
                              void* d_out, int out_size, void* d_ws, size_t ws_size,
                              hipStream_t stream) {
    const int*   x    = (const int*)d_in[0];
    const float* eemb = (const float*)d_in[1];
    const float* ecw  = (const float*)d_in[2];
    const float* ecb  = (const float*)d_in[3];
    const float* elw  = (const float*)d_in[4];
    const float* elb  = (const float*)d_in[5];
    // d_in[6] rand_proj: provably unused (fog_of_war returns identity permutation)
    const float* mcw  = (const float*)d_in[7];
    const float* mcb  = (const float*)d_in[8];
    const float* mlw  = (const float*)d_in[9];
    const float* mlb  = (const float*)d_in[10];
    const float* femb = (const float*)d_in[11];
    const float* fcw  = (const float*)d_in[12];
    const float* fcb  = (const float*)d_in[13];
    const float* flw1 = (const float*)d_in[14];
    const float* flb1 = (const float*)d_in[15];
    const float* fl2  = (const float*)d_in[16];
    const float* fb2  = (const float*)d_in[17];
    float* outp = (float*)d_out;

    char* w = (char*)d_ws;
    size_t off = 0;
    auto alloc = [&](size_t bytes) {
        void* p = w + off;
        off = (off + bytes + 255) & ~(size_t)255;
        return p;
    };
    float* P      = (float*)alloc(2ull * NP * EMBD * 4);        // 0.8 MB
    float* cwT    = (float*)alloc(2ull * 3 * EMBD * OC * 4);    // 3.1 MB
    float* C      = (float*)alloc(2ull * NP * 3 * OC * 4);      // 1.2 MB
    float* Wc     = (float*)alloc(3ull * 128 * 64 * 4);
    float* Lint   = (float*)alloc(64ull * MJ * 4);
    int*   tokens = (int*)alloc((size_t)BB * LL * 4);
    float* partial= (float*)alloc((size_t)BB * H2 * JD * 4);    // 16.8 MB, [b][h][j]

    const float* C_e = C;
    const float* C_f = C + (size_t)NP * 3 * OC;

    // ---- prep (pairs | cwt | manipw | lint) ----
    k_prep<<<PB_PAIRS + PB_CWT + PB_MANIPW + PB_LINT, 256, 0, stream>>>(
        eemb, femb, ecw, fcw, mcw, mlw, P, cwT, Wc, Lint);
    // ---- pair contributions (full K, q-batch 4, cb folded) ----
    k_contrib<<<2 * 3 * 49, 256, 0, stream>>>(P, cwT, ecb, fcb, C);

    // ---- enemy branch (bf16x3 MFMA — token path needs near-fp32) ----
    k_gemm<1><<<dim3(H2, 4), 512, 0, stream>>>(x, C_e, elw, partial);
    k_fuseE<<<BB, 256, 0, stream>>>(partial, elb, Wc, mcb, mlw, Lint, mlb, tokens);

    // ---- friend branch (plain bf16 MFMA) ----
    k_gemm<0><<<dim3(H2, 4), 512, 0, stream>>>(tokens, C_f, flw1, partial);
    k_fuseF<<<BB, 256, 0, stream>>>(partial, flb1, fl2, fb2, outp);
}